// Round 21
// baseline (1763.932 us; speedup 1.0000x reference)
//
#include <hip/hip_runtime.h>
#include <hip/hip_bf16.h>

typedef __hip_bfloat16 bf16;
typedef unsigned short u16x8 __attribute__((ext_vector_type(8)));
using v8s = __attribute__((ext_vector_type(8))) short;   // bf16 x8 MFMA frag (4 VGPR)
using v4f = __attribute__((ext_vector_type(4))) float;   // f32 x4 acc frag

#define L_SEQ 2048
#define BATCH 8
#define NIN   1024    // 2H
#define WLD   3072    // W row stride, layers 1-3
#define NHALF 1536    // per-direction columns (3*H)
#define NROWS (L_SEQ*BATCH)
#define L2E   1.4426950408889634f

__device__ __forceinline__ float bits2f(unsigned short u){ return __uint_as_float(((unsigned)u)<<16); }
__device__ __forceinline__ float b2f(bf16 v){ return __bfloat162float(v); }
__device__ __forceinline__ bf16  f2b(float v){ return __float2bfloat16(v); }

__device__ __forceinline__ void gload16(const void* g, void* l){
    __builtin_amdgcn_global_load_lds((const __attribute__((address_space(1))) void*)g,
                                     (__attribute__((address_space(3))) void*)l, 16, 0, 0);
}

__global__ void k_code(float* __restrict__ out, float v){
    if (threadIdx.x == 0 && blockIdx.x == 0) out[0] = v;
}

// ---------------- dxT[b][l] = X[b][l] - X[b][l-1], 0 at l=0  ((B,L) layout)
__global__ __launch_bounds__(256) void k_diff(const float* __restrict__ X, float* __restrict__ dxT){
    int i = blockIdx.x*256 + threadIdx.x;
    if (i >= NROWS) return;
    int l = i & (L_SEQ-1);
    float v = 0.f;
    if (l > 0) v = X[i] - X[i-1];
    dxT[i] = v;
}

// ---------------- W (fp32 [1024][3072]) -> Wt (bf16 [3072][1024], transposed)
__global__ __launch_bounds__(256) void k_wt(const float* __restrict__ W, bf16* __restrict__ Wt){
    __shared__ float t[32][33];
    int k0 = blockIdx.x*32, n0 = blockIdx.y*32;
    int tx = threadIdx.x & 31, ty = threadIdx.x >> 5;   // ty 0..7
    #pragma unroll
    for (int j=0;j<4;j++)
        t[ty*4+j][tx] = W[(size_t)(k0+ty*4+j)*WLD + n0 + tx];
    __syncthreads();
    #pragma unroll
    for (int j=0;j<4;j++)
        Wt[(size_t)(n0+ty*4+j)*NIN + k0 + tx] = f2b(t[tx][ty*4+j]);
}

// ---------------- layer 0: chain/post split (round-19/20 version)
__global__ __launch_bounds__(256) void k_layer0(const float* __restrict__ dxT, const float* __restrict__ W0,
                                                const float* __restrict__ wc, const float* __restrict__ bb,
                                                bf16* __restrict__ xout){
    __shared__ float sdx[L_SEQ];
    int g = blockIdx.x*256 + threadIdx.x;           // 8192 threads: (d,b,h); b,d block-uniform
    int h = g & 511, b = (g>>9) & 7, d = g >> 12;
    const float* dxp = dxT + b*L_SEQ;
    for (int t = threadIdx.x; t < L_SEQ; t += 256) sdx[t] = dxp[t];
    __syncthreads();

    int dcol = d*512 + h;
    float w0  = W0[d*2048 + h];
    float w1L = W0[d*2048 + 512 + h]*L2E;
    float w2L = W0[d*2048 + 1024 + h]*L2E;
    float w3  = W0[d*2048 + 1536 + h];
    float vfL = wc[dcol]*L2E,  vrL = wc[1024 + dcol]*L2E;
    float bfvL = bb[dcol]*L2E, brvL = bb[1024 + dcol]*L2E;
    float c = 0.f;

    int t0 = d ? (L_SEQ-1) : 0;
    bf16* xq = xout + ((size_t)t0*BATCH + b)*NIN + dcol;
    ptrdiff_t xs = d ? -(ptrdiff_t)(BATCH*NIN) : (ptrdiff_t)(BATCH*NIN);

#define LD0(P0,P1,P2,P3, s0) do{                                     \
        _Pragma("unroll")                                            \
        for (int i_=0;i_<8;i_++){                                    \
            int ss_ = (s0)+i_;                                       \
            float xv_ = sdx[d ? (L_SEQ-1-ss_) : ss_];                \
            P0[i_] = xv_*w0;                                         \
            P1[i_] = fmaf(xv_, w1L, bfvL);                           \
            P2[i_] = fmaf(xv_, w2L, brvL);                           \
            P3[i_] = xv_*w3;                                         \
        }                                                            \
        __builtin_amdgcn_sched_barrier(0);                           \
    }while(0)

#define STEP8(P0,P1,P2,P3) do{                                       \
        float cs_[8];                                                \
        _Pragma("unroll")                                            \
        for (int i_=0;i_<8;i_++){                                    \
            float e_ = exp2f(fmaf(-vfL, c, -P1[i_]));                \
            float f_ = __builtin_amdgcn_rcpf(1.f + e_);              \
            c = fmaf(f_, c - P0[i_], P0[i_]);                        \
            cs_[i_] = c;                                             \
        }                                                            \
        __builtin_amdgcn_sched_barrier(0);                           \
        _Pragma("unroll")                                            \
        for (int i_=0;i_<8;i_++){                                    \
            float e2_ = exp2f(fmaf(-vrL, cs_[i_], -P2[i_]));         \
            float r_ = __builtin_amdgcn_rcpf(1.f + e2_);             \
            xq[(ptrdiff_t)i_*xs] = f2b(fmaf(r_, cs_[i_]-P3[i_], P3[i_])); \
        }                                                            \
        xq += 8*xs;                                                  \
        __builtin_amdgcn_sched_barrier(0);                           \
    }while(0)

    float A0[8],A1[8],A2[8],A3[8], B0[8],B1[8],B2[8],B3[8];
    LD0(A0,A1,A2,A3, 0);
    for (int s0 = 0; s0 + 32 <= L_SEQ; s0 += 16){
        LD0(B0,B1,B2,B3, s0+8);
        STEP8(A0,A1,A2,A3);
        LD0(A0,A1,A2,A3, s0+16);
        STEP8(B0,B1,B2,B3);
    }
    LD0(B0,B1,B2,B3, L_SEQ-8);
    STEP8(A0,A1,A2,A3);
    STEP8(B0,B1,B2,B3);
#undef LD0
#undef STEP8
}

// ---------------- MFMA GEMM: UcH[set s] = x[all rows] @ Wt[set s]^T   (bf16 output, unchanged)
__global__ __launch_bounds__(256) void k_gemm(const bf16* __restrict__ Xin, const bf16* __restrict__ Wt,
                                              bf16* __restrict__ Uc, int l0, int C){
    __shared__ bf16 As[3][4096];   // [buf][128 m][32 k], 64B rows (8KB/buf)
    __shared__ bf16 Bs[3][4096];
    int tid = threadIdx.x;
    int lane = tid & 63;
    int s = blockIdx.z;
    int base = (s == 0) ? l0 : (L_SEQ - l0 - C);
    const bf16* A  = Xin + (size_t)base*BATCH*NIN;
    const bf16* Bm = Wt + (size_t)s*NHALF*NIN;
    bf16*       Cc = Uc + (size_t)s*(size_t)C*BATCH*NHALF;

    int m0 = blockIdx.x*128, n0 = blockIdx.y*128;
    int wv = tid >> 6;
    int wm = (wv >> 1)*64, wn = (wv & 1)*64;

    v4f acc[4][4];
    #pragma unroll
    for (int i=0;i<4;i++)
        #pragma unroll
        for (int j=0;j<4;j++)
            #pragma unroll
            for (int r=0;r<4;r++) acc[i][j][r] = 0.f;

    int row_a = tid >> 2;
    int kb = (((tid & 3) ^ ((tid >> 3) & 3)))*8;            // source-side swizzle
    int wbase = (tid & 192)*16;
    int fro = (lane & 15)*64 + (((lane >> 4) ^ (((lane & 15) >> 1) & 3)))*16;  // read-side swizzle

#define STAGE(q, k0) do{                                                        \
        char* la_ = (char*)As[0] + (q)*8192;                                    \
        char* lb_ = (char*)Bs[0] + (q)*8192;                                    \
        gload16(A  + (size_t)(m0 + row_a      )*NIN + (k0) + kb, la_ + wbase);  \
        gload16(A  + (size_t)(m0 + row_a + 64 )*NIN + (k0) + kb, la_ + 4096 + wbase); \
        gload16(Bm + (size_t)(n0 + row_a      )*NIN + (k0) + kb, lb_ + wbase);  \
        gload16(Bm + (size_t)(n0 + row_a + 64 )*NIN + (k0) + kb, lb_ + 4096 + wbase); \
    }while(0)

    STAGE(0, 0);
    STAGE(1, 32);
    int cur = 0;
    for (int it = 0; it < 32; ++it){
        if (it < 30){
            int nb = cur + 2; if (nb >= 3) nb -= 3;
            STAGE(nb, (it+2)*32);
            asm volatile("s_waitcnt vmcnt(8)" ::: "memory");   // drain tile-it (2 iters old)
        } else if (it == 30){
            asm volatile("s_waitcnt vmcnt(4)" ::: "memory");
        } else {
            asm volatile("s_waitcnt vmcnt(0)" ::: "memory");
        }
        __builtin_amdgcn_sched_barrier(0);
        __builtin_amdgcn_s_barrier();
        const char* la = (const char*)As[0] + cur*8192;
        const char* lb = (const char*)Bs[0] + cur*8192;
        v8s av[4], bv[4];
        #pragma unroll
        for (int i=0;i<4;i++) av[i] = *(const v8s*)(la + (wm + i*16)*64 + fro);
        #pragma unroll
        for (int j=0;j<4;j++) bv[j] = *(const v8s*)(lb + (wn + j*16)*64 + fro);
        #pragma unroll
        for (int i=0;i<4;i++)
            #pragma unroll
            for (int j=0;j<4;j++)
                acc[i][j] = __builtin_amdgcn_mfma_f32_16x16x32_bf16(av[i], bv[j], acc[i][j], 0, 0, 0);
        __builtin_amdgcn_s_barrier();
        cur = cur + 1; if (cur == 3) cur = 0;
    }
#undef STAGE

    int cr = (lane >> 4)*4, ccol = lane & 15;
    #pragma unroll
    for (int i=0;i<4;i++){
        #pragma unroll
        for (int j=0;j<4;j++){
            size_t rb = (size_t)(m0 + wm + i*16 + cr)*NHALF + (n0 + wn + j*16 + ccol);
            #pragma unroll
            for (int r=0;r<4;r++) Cc[rb + (size_t)r*NHALF] = f2b(acc[i][j][r]);
        }
    }
}

// ---------------- recurrence, layers 1-3: PAIRED directions per wave (latency-regime fix).
// 64 blocks x 64 threads: block owns (b, 64-ch slice), BOTH directions. Two independent
// chains per thread interleave in the issue stream, filling exp2/rcp latency bubbles.
// Phased RCOMP caps VGPR: (A) chain inputs only, (B) dual chains, (C) post+stores.
// 16 gloads/group; vmcnt steady 48 (= S(g-1)32 + L(g+1)16 newer than L(g)16), tail 32.
__global__ __launch_bounds__(64) void k_rec(const bf16* __restrict__ Uc, const bf16* __restrict__ xin,
                                            bf16* __restrict__ xout, float* __restrict__ carry,
                                            const float* __restrict__ wc, const float* __restrict__ bb,
                                            int l0, int C){
    __shared__ bf16 Uf[2][3072];    // fwd U  [seg=step*3+gate][64]  2x6KB
    __shared__ bf16 Uw[2][3072];    // bwd U                         2x6KB
    __shared__ bf16 Xf[2][1024];    // fwd x rows                    2x2KB
    __shared__ bf16 Xw[2][1024];    // bwd x rows                    2x2KB
    int tid = threadIdx.x;          // 0..63
    int bid = blockIdx.x;           // 0..63
    int b = bid >> 3, hbase = (bid & 7)*64;
    int h = hbase + tid;
    // fwd: d=0, dcol=h ; bwd: d=1, dcol=512+h
    float vf0 = wc[h]*L2E,     vr0 = wc[1024+h]*L2E;
    float bf0 = bb[h]*L2E,     br0 = bb[1024+h]*L2E;
    float vf1 = wc[512+h]*L2E, vr1 = wc[1536+h]*L2E;
    float bf1 = bb[512+h]*L2E, br1 = bb[1536+h]*L2E;
    int ch0 = b*512 + h, ch1 = 4096 + b*512 + h;
    float c0 = (l0 == 0) ? 0.f : carry[ch0];
    float c1 = (l0 == 0) ? 0.f : carry[ch1];

    const bf16* Ub0 = Uc + b*1536 + hbase;                        // set 0, rows ascend
    const bf16* Ub1 = Uc + (size_t)C*12288 + b*1536 + hbase;      // set 1, rows descend
    int lo3 = tid >> 3, ci8 = (tid & 7)*8;

#define RSTAGE(base_, q_) do{                                                   \
        char* uf_ = (char*)Uf[q_]; char* uw_ = (char*)Uw[q_];                   \
        char* xf_ = (char*)Xf[q_]; char* xw_ = (char*)Xw[q_];                   \
        _Pragma("unroll")                                                       \
        for (int qq=0; qq<6; ++qq){                                             \
            int seg = qq*8 + lo3;                                               \
            int st_ = seg/3, gate_ = seg - st_*3;                               \
            int sf_ = (base_) + st_;                                            \
            gload16(Ub0 + (size_t)sf_*12288 + gate_*512 + ci8, uf_ + qq*1024);  \
            gload16(Ub1 + (size_t)(C-1-sf_)*12288 + gate_*512 + ci8, uw_ + qq*1024); \
        }                                                                       \
        _Pragma("unroll")                                                       \
        for (int j=0;j<2;++j){                                                  \
            int st_ = (base_) + j*8 + lo3;                                      \
            int tf_ = l0 + st_;                                                 \
            int tb_ = L_SEQ-1 - l0 - st_;                                       \
            gload16(xin + ((size_t)tf_*BATCH + b)*NIN + hbase + ci8,       xf_ + j*1024); \
            gload16(xin + ((size_t)tb_*BATCH + b)*NIN + 512 + hbase + ci8, xw_ + j*1024); \
        }                                                                       \
    }while(0)

#define RCOMP(base_, q_) do{                                                    \
        float a0[16],a1[16],g0[16],g1[16],cs0[16],cs1[16];                      \
        _Pragma("unroll")                                                       \
        for (int i_=0;i_<16;i_++){                                              \
            a0[i_] = b2f(Uf[q_][(i_*3+0)*64+tid]);                              \
            a1[i_] = fmaf(b2f(Uf[q_][(i_*3+1)*64+tid]), L2E, bf0);              \
            g0[i_] = b2f(Uw[q_][(i_*3+0)*64+tid]);                              \
            g1[i_] = fmaf(b2f(Uw[q_][(i_*3+1)*64+tid]), L2E, bf1);              \
        }                                                                       \
        __builtin_amdgcn_sched_barrier(0);                                      \
        _Pragma("unroll")                                                       \
        for (int i_=0;i_<16;i_++){                                              \
            float e0_ = exp2f(fmaf(-vf0, c0, -a1[i_]));                         \
            float e1_ = exp2f(fmaf(-vf1, c1, -g1[i_]));                         \
            float f0_ = __builtin_amdgcn_rcpf(1.f + e0_);                       \
            float f1_ = __builtin_amdgcn_rcpf(1.f + e1_);                       \
            c0 = fmaf(f0_, c0 - a0[i_], a0[i_]);  cs0[i_] = c0;                 \
            c1 = fmaf(f1_, c1 - g0[i_], g0[i_]);  cs1[i_] = c1;                 \
        }                                                                       \
        __builtin_amdgcn_sched_barrier(0);                                      \
        bf16* xq0 = xout + ((size_t)(l0 + (base_))*BATCH + b)*NIN + h;          \
        bf16* xq1 = xout + ((size_t)(L_SEQ-1 - l0 - (base_))*BATCH + b)*NIN + 512 + h; \
        _Pragma("unroll")                                                       \
        for (int i_=0;i_<16;i_++){                                              \
            float u2f_ = fmaf(b2f(Uf[q_][(i_*3+2)*64+tid]), L2E, br0);          \
            float xrf_ = b2f(Xf[q_][i_*64+tid]);                                \
            float e2_ = exp2f(fmaf(-vr0, cs0[i_], -u2f_));                      \
            float r0_ = __builtin_amdgcn_rcpf(1.f + e2_);                       \
            xq0[(ptrdiff_t)i_*(BATCH*NIN)] = f2b(fmaf(r0_, cs0[i_]-xrf_, xrf_)); \
            float u2b_ = fmaf(b2f(Uw[q_][(i_*3+2)*64+tid]), L2E, br1);          \
            float xrb_ = b2f(Xw[q_][i_*64+tid]);                                \
            float e3_ = exp2f(fmaf(-vr1, cs1[i_], -u2b_));                      \
            float r1_ = __builtin_amdgcn_rcpf(1.f + e3_);                       \
            xq1[-(ptrdiff_t)i_*(BATCH*NIN)] = f2b(fmaf(r1_, cs1[i_]-xrb_, xrb_)); \
        }                                                                       \
    }while(0)

    RSTAGE(0, 0);
    asm volatile("s_waitcnt vmcnt(0)" ::: "memory");
    __builtin_amdgcn_sched_barrier(0);
    int ngrp = C >> 4;
    for (int g = 0; g < ngrp; ++g){
        int q = g & 1;
        if (g + 1 < ngrp){
            RSTAGE((g+1)*16, q^1);                           // queue: L(g)16 | S(g-1)32 | L(g+1)16
            asm volatile("s_waitcnt vmcnt(48)" ::: "memory");// drain exactly L(g)
        } else {
            asm volatile("s_waitcnt vmcnt(32)" ::: "memory");// queue: L(g)16 | S(g-1)32
        }
        __builtin_amdgcn_sched_barrier(0);
        RCOMP(g*16, q);
    }
    carry[ch0] = c0;
    carry[ch1] = c1;
#undef RSTAGE
#undef RCOMP
}

// ---------------- classifier: out[(b*L + l)*3 + j] = h[row l*8+b] @ Wcls + bcls
__global__ __launch_bounds__(256) void k_cls(const bf16* __restrict__ Xf, const float* __restrict__ Wc,
                                             const float* __restrict__ bc, float* __restrict__ out){
    int wave = threadIdx.x >> 6, lane = threadIdx.x & 63;
    int row = blockIdx.x*4 + wave;                  // row = l*8+b
    const bf16* xp = Xf + (size_t)row*NIN + lane*16;
    u16x8 v0 = *(const u16x8*)(xp);
    u16x8 v1 = *(const u16x8*)(xp + 8);
    float a0=0.f, a1=0.f, a2=0.f;
    #pragma unroll
    for (int i=0;i<16;i++){
        float xv = bits2f(i<8 ? v0[i&7] : v1[i&7]);
        int k = lane*16 + i;
        a0 += xv*Wc[k*3+0];
        a1 += xv*Wc[k*3+1];
        a2 += xv*Wc[k*3+2];
    }
    #pragma unroll
    for (int off=32; off; off>>=1){
        a0 += __shfl_down(a0, off);
        a1 += __shfl_down(a1, off);
        a2 += __shfl_down(a2, off);
    }
    if (lane == 0){
        int l = row >> 3, b = row & 7;
        float* op = out + ((size_t)b*L_SEQ + l)*3;
        op[0] = a0 + bc[0];
        op[1] = a1 + bc[1];
        op[2] = a2 + bc[2];
    }
}

// ----------------------------------------------------------------
extern "C" void kernel_launch(void* const* d_in, const int* in_sizes, int n_in,
                              void* d_out, int out_size, void* d_ws, size_t ws_size,
                              hipStream_t stream){
    (void)in_sizes; (void)n_in; (void)out_size;
    const float* X    = (const float*)d_in[0];
    const float* W[4]  = {(const float*)d_in[1],(const float*)d_in[4],(const float*)d_in[7],(const float*)d_in[10]};
    const float* wc[4] = {(const float*)d_in[2],(const float*)d_in[5],(const float*)d_in[8],(const float*)d_in[11]};
    const float* bb[4] = {(const float*)d_in[3],(const float*)d_in[6],(const float*)d_in[9],(const float*)d_in[12]};
    const float* Wcls = (const float*)d_in[13];
    const float* bcls = (const float*)d_in[14];
    float* out = (float*)d_out;

    // workspace layout:
    //   xA    bf16[16384*1024]  @ 0           33,554,432
    //   xB    bf16[16384*1024]  @ 33554432    33,554,432
    //   dxT   f32 [8*2048]      @ 67108864        65,536
    //   carry f32 [8192]        @ 67174400        32,768
    //   Wt0-2 bf16[3072*1024]   @ 67207168    3 x 6,291,456
    //   Ucb   bf16[C*2*8*1536]  @ 86081536    C*49,152   (C=2048 -> 100MB)
    char*  ws    = (char*)d_ws;
    bf16*  xA    = (bf16*)ws;
    bf16*  xB    = (bf16*)(ws + 33554432);
    float* dxT   = (float*)(ws + 67108864);
    float* carry = (float*)(ws + 67174400);
    bf16*  Wt[3] = {(bf16*)(ws + 67207168), (bf16*)(ws + 73498624), (bf16*)(ws + 79790080)};
    bf16*  Ucb   = (bf16*)(ws + 86081536);
    const size_t NEEDED = 86081536ull + 64ull*49152ull;

    if (ws_size < NEEDED){
        float code = 1.0e6f + (float)((ws_size >> 20) > 9999 ? 9999 : (ws_size >> 20)) * 100.0f;
        k_code<<<1, 64, 0, stream>>>(out, code);
        return;
    }

    int C = 2048;
    while (C > 64 && 86081536ull + (size_t)C*49152ull > ws_size) C >>= 1;

    k_diff  <<<(NROWS+255)/256, 256, 0, stream>>>(X, dxT);
    for (int i = 0; i < 3; ++i)
        k_wt<<<dim3(32,96), 256, 0, stream>>>(W[i+1], Wt[i]);
    k_layer0<<<32, 256, 0, stream>>>(dxT, W[0], wc[0], bb[0], xA);

    bf16* xin = xA; bf16* xo = xB;
    for (int layer = 1; layer < 4; ++layer){
        for (int l0 = 0; l0 < L_SEQ; l0 += C){
            dim3 g(C*8/128, NHALF/128, 2);
            k_gemm<<<g, 256, 0, stream>>>(xin, Wt[layer-1], Ucb, l0, C);
            k_rec <<<64, 64, 0, stream>>>(Ucb, xin, xo, carry, wc[layer], bb[layer], l0, C);
        }
        bf16* t = xin; xin = xo; xo = t;
    }
    k_cls<<<NROWS/4, 256, 0, stream>>>(xin, Wcls, bcls, out);
}

// Round 22
// 1324.912 us; speedup vs baseline: 1.3314x; 1.3314x over previous
//
#include <hip/hip_runtime.h>
#include <hip/hip_bf16.h>

typedef __hip_bfloat16 bf16;
typedef unsigned short u16x8 __attribute__((ext_vector_type(8)));
using v8s = __attribute__((ext_vector_type(8))) short;   // bf16 x8 MFMA frag (4 VGPR)
using v4f = __attribute__((ext_vector_type(4))) float;   // f32 x4 acc frag

#define L_SEQ 2048
#define BATCH 8
#define NIN   1024    // 2H
#define WLD   3072    // W row stride, layers 1-3
#define NHALF 1536    // per-direction columns (3*H)
#define NROWS (L_SEQ*BATCH)
#define L2E   1.4426950408889634f

__device__ __forceinline__ float bits2f(unsigned short u){ return __uint_as_float(((unsigned)u)<<16); }
__device__ __forceinline__ float b2f(bf16 v){ return __bfloat162float(v); }
__device__ __forceinline__ bf16  f2b(float v){ return __float2bfloat16(v); }

__device__ __forceinline__ void gload16(const void* g, void* l){
    __builtin_amdgcn_global_load_lds((const __attribute__((address_space(1))) void*)g,
                                     (__attribute__((address_space(3))) void*)l, 16, 0, 0);
}

__global__ void k_code(float* __restrict__ out, float v){
    if (threadIdx.x == 0 && blockIdx.x == 0) out[0] = v;
}

// ---------------- dxT[b][l] = X[b][l] - X[b][l-1], 0 at l=0  ((B,L) layout)
__global__ __launch_bounds__(256) void k_diff(const float* __restrict__ X, float* __restrict__ dxT){
    int i = blockIdx.x*256 + threadIdx.x;
    if (i >= NROWS) return;
    int l = i & (L_SEQ-1);
    float v = 0.f;
    if (l > 0) v = X[i] - X[i-1];
    dxT[i] = v;
}

// ---------------- W (fp32 [1024][3072]) -> Wt (bf16 [3072][1024], transposed)
__global__ __launch_bounds__(256) void k_wt(const float* __restrict__ W, bf16* __restrict__ Wt){
    __shared__ float t[32][33];
    int k0 = blockIdx.x*32, n0 = blockIdx.y*32;
    int tx = threadIdx.x & 31, ty = threadIdx.x >> 5;   // ty 0..7
    #pragma unroll
    for (int j=0;j<4;j++)
        t[ty*4+j][tx] = W[(size_t)(k0+ty*4+j)*WLD + n0 + tx];
    __syncthreads();
    #pragma unroll
    for (int j=0;j<4;j++)
        Wt[(size_t)(n0+ty*4+j)*NIN + k0 + tx] = f2b(t[tx][ty*4+j]);
}

// ---------------- layer 0: chain/post split (round-19/20 version)
__global__ __launch_bounds__(256) void k_layer0(const float* __restrict__ dxT, const float* __restrict__ W0,
                                                const float* __restrict__ wc, const float* __restrict__ bb,
                                                bf16* __restrict__ xout){
    __shared__ float sdx[L_SEQ];
    int g = blockIdx.x*256 + threadIdx.x;           // 8192 threads: (d,b,h); b,d block-uniform
    int h = g & 511, b = (g>>9) & 7, d = g >> 12;
    const float* dxp = dxT + b*L_SEQ;
    for (int t = threadIdx.x; t < L_SEQ; t += 256) sdx[t] = dxp[t];
    __syncthreads();

    int dcol = d*512 + h;
    float w0  = W0[d*2048 + h];
    float w1L = W0[d*2048 + 512 + h]*L2E;
    float w2L = W0[d*2048 + 1024 + h]*L2E;
    float w3  = W0[d*2048 + 1536 + h];
    float vfL = wc[dcol]*L2E,  vrL = wc[1024 + dcol]*L2E;
    float bfvL = bb[dcol]*L2E, brvL = bb[1024 + dcol]*L2E;
    float c = 0.f;

    int t0 = d ? (L_SEQ-1) : 0;
    bf16* xq = xout + ((size_t)t0*BATCH + b)*NIN + dcol;
    ptrdiff_t xs = d ? -(ptrdiff_t)(BATCH*NIN) : (ptrdiff_t)(BATCH*NIN);

#define LD0(P0,P1,P2,P3, s0) do{                                     \
        _Pragma("unroll")                                            \
        for (int i_=0;i_<8;i_++){                                    \
            int ss_ = (s0)+i_;                                       \
            float xv_ = sdx[d ? (L_SEQ-1-ss_) : ss_];                \
            P0[i_] = xv_*w0;                                         \
            P1[i_] = fmaf(xv_, w1L, bfvL);                           \
            P2[i_] = fmaf(xv_, w2L, brvL);                           \
            P3[i_] = xv_*w3;                                         \
        }                                                            \
        __builtin_amdgcn_sched_barrier(0);                           \
    }while(0)

#define STEP8(P0,P1,P2,P3) do{                                       \
        float cs_[8];                                                \
        _Pragma("unroll")                                            \
        for (int i_=0;i_<8;i_++){                                    \
            float e_ = exp2f(fmaf(-vfL, c, -P1[i_]));                \
            float f_ = __builtin_amdgcn_rcpf(1.f + e_);              \
            c = fmaf(f_, c - P0[i_], P0[i_]);                        \
            cs_[i_] = c;                                             \
        }                                                            \
        __builtin_amdgcn_sched_barrier(0);                           \
        _Pragma("unroll")                                            \
        for (int i_=0;i_<8;i_++){                                    \
            float e2_ = exp2f(fmaf(-vrL, cs_[i_], -P2[i_]));         \
            float r_ = __builtin_amdgcn_rcpf(1.f + e2_);             \
            xq[(ptrdiff_t)i_*xs] = f2b(fmaf(r_, cs_[i_]-P3[i_], P3[i_])); \
        }                                                            \
        xq += 8*xs;                                                  \
        __builtin_amdgcn_sched_barrier(0);                           \
    }while(0)

    float A0[8],A1[8],A2[8],A3[8], B0[8],B1[8],B2[8],B3[8];
    LD0(A0,A1,A2,A3, 0);
    for (int s0 = 0; s0 + 32 <= L_SEQ; s0 += 16){
        LD0(B0,B1,B2,B3, s0+8);
        STEP8(A0,A1,A2,A3);
        LD0(A0,A1,A2,A3, s0+16);
        STEP8(B0,B1,B2,B3);
    }
    LD0(B0,B1,B2,B3, L_SEQ-8);
    STEP8(A0,A1,A2,A3);
    STEP8(B0,B1,B2,B3);
#undef LD0
#undef STEP8
}

// ---------------- MFMA GEMM: UcH[set s] = x[all rows] @ Wt[set s]^T   (bf16 output, unchanged)
__global__ __launch_bounds__(256) void k_gemm(const bf16* __restrict__ Xin, const bf16* __restrict__ Wt,
                                              bf16* __restrict__ Uc, int l0, int C){
    __shared__ bf16 As[3][4096];   // [buf][128 m][32 k], 64B rows (8KB/buf)
    __shared__ bf16 Bs[3][4096];
    int tid = threadIdx.x;
    int lane = tid & 63;
    int s = blockIdx.z;
    int base = (s == 0) ? l0 : (L_SEQ - l0 - C);
    const bf16* A  = Xin + (size_t)base*BATCH*NIN;
    const bf16* Bm = Wt + (size_t)s*NHALF*NIN;
    bf16*       Cc = Uc + (size_t)s*(size_t)C*BATCH*NHALF;

    int m0 = blockIdx.x*128, n0 = blockIdx.y*128;
    int wv = tid >> 6;
    int wm = (wv >> 1)*64, wn = (wv & 1)*64;

    v4f acc[4][4];
    #pragma unroll
    for (int i=0;i<4;i++)
        #pragma unroll
        for (int j=0;j<4;j++)
            #pragma unroll
            for (int r=0;r<4;r++) acc[i][j][r] = 0.f;

    int row_a = tid >> 2;
    int kb = (((tid & 3) ^ ((tid >> 3) & 3)))*8;            // source-side swizzle
    int wbase = (tid & 192)*16;
    int fro = (lane & 15)*64 + (((lane >> 4) ^ (((lane & 15) >> 1) & 3)))*16;  // read-side swizzle

#define STAGE(q, k0) do{                                                        \
        char* la_ = (char*)As[0] + (q)*8192;                                    \
        char* lb_ = (char*)Bs[0] + (q)*8192;                                    \
        gload16(A  + (size_t)(m0 + row_a      )*NIN + (k0) + kb, la_ + wbase);  \
        gload16(A  + (size_t)(m0 + row_a + 64 )*NIN + (k0) + kb, la_ + 4096 + wbase); \
        gload16(Bm + (size_t)(n0 + row_a      )*NIN + (k0) + kb, lb_ + wbase);  \
        gload16(Bm + (size_t)(n0 + row_a + 64 )*NIN + (k0) + kb, lb_ + 4096 + wbase); \
    }while(0)

    STAGE(0, 0);
    STAGE(1, 32);
    int cur = 0;
    for (int it = 0; it < 32; ++it){
        if (it < 30){
            int nb = cur + 2; if (nb >= 3) nb -= 3;
            STAGE(nb, (it+2)*32);
            asm volatile("s_waitcnt vmcnt(8)" ::: "memory");   // drain tile-it (2 iters old)
        } else if (it == 30){
            asm volatile("s_waitcnt vmcnt(4)" ::: "memory");
        } else {
            asm volatile("s_waitcnt vmcnt(0)" ::: "memory");
        }
        __builtin_amdgcn_sched_barrier(0);
        __builtin_amdgcn_s_barrier();
        const char* la = (const char*)As[0] + cur*8192;
        const char* lb = (const char*)Bs[0] + cur*8192;
        v8s av[4], bv[4];
        #pragma unroll
        for (int i=0;i<4;i++) av[i] = *(const v8s*)(la + (wm + i*16)*64 + fro);
        #pragma unroll
        for (int j=0;j<4;j++) bv[j] = *(const v8s*)(lb + (wn + j*16)*64 + fro);
        #pragma unroll
        for (int i=0;i<4;i++)
            #pragma unroll
            for (int j=0;j<4;j++)
                acc[i][j] = __builtin_amdgcn_mfma_f32_16x16x32_bf16(av[i], bv[j], acc[i][j], 0, 0, 0);
        __builtin_amdgcn_s_barrier();
        cur = cur + 1; if (cur == 3) cur = 0;
    }
#undef STAGE

    int cr = (lane >> 4)*4, ccol = lane & 15;
    #pragma unroll
    for (int i=0;i<4;i++){
        #pragma unroll
        for (int j=0;j<4;j++){
            size_t rb = (size_t)(m0 + wm + i*16 + cr)*NHALF + (n0 + wn + j*16 + ccol);
            #pragma unroll
            for (int r=0;r<4;r++) Cc[rb + (size_t)r*NHALF] = f2b(acc[i][j][r]);
        }
    }
}

// ---------------- recurrence, layers 1-3: single-wave blocks, zero barriers, 16-step groups.
// ROUND 22: phase-A batch carries ONLY the chain inputs (u0,u1L = 32 floats) so the
// allocator keeps them in registers (round-20 VGPR=68 proved it sank the 80-float batch).
// u2L/xr load in phase C where 16 independent iterations self-hide LDS latency.
__global__ __launch_bounds__(64) void k_rec(const bf16* __restrict__ Uc, const bf16* __restrict__ xin,
                                            bf16* __restrict__ xout, float* __restrict__ carry,
                                            const float* __restrict__ wc, const float* __restrict__ bb,
                                            int l0, int C){
    __shared__ bf16 Ub[2][3072];    // [buf][seg=step*3+gate][64 bf16]  2x6KB
    __shared__ bf16 Xb[2][1024];    // [buf][step][64 bf16]             2x2KB
    int tid = threadIdx.x;          // 0..63
    int bid = blockIdx.x;           // 0..127
    int d = bid >> 6, b = (bid >> 3) & 7, hbase = (bid & 7)*64;
    int h = hbase + tid;
    int dcol = d*512 + h;
    int ch = d*4096 + b*512 + h;
    float vfL = wc[d*512 + h]*L2E, vrL = wc[1024 + d*512 + h]*L2E;
    float bfvL = bb[d*512 + h]*L2E, brvL = bb[1024 + d*512 + h]*L2E;
    float c = (l0 == 0) ? 0.f : carry[ch];

    const bf16* Ubase = Uc + (size_t)d*(size_t)C*12288 + b*1536 + hbase;   // row stride 12288 bf16
    int lo3 = tid >> 3, ci8 = (tid & 7)*8;   // seg-sublane split: 8 lanes x 16B per 128B seg

#define RSTAGE(base_, q_) do{                                                   \
        char* ub_ = (char*)Ub[q_]; char* xb_ = (char*)Xb[q_];                   \
        _Pragma("unroll")                                                       \
        for (int qq=0; qq<6; ++qq){                                             \
            int seg = qq*8 + lo3;                   /* 0..47 */                 \
            int st_ = seg/3, gate_ = seg - st_*3;                               \
            int ss_ = (base_) + st_;                                            \
            int row_ = d ? (C-1-ss_) : ss_;                                     \
            gload16(Ubase + (size_t)row_*12288 + gate_*512 + ci8,               \
                    ub_ + qq*1024);                                             \
        }                                                                       \
        _Pragma("unroll")                                                       \
        for (int j=0;j<2;++j){                                                  \
            int st_ = (base_) + j*8 + lo3;                                      \
            int t_  = d ? (L_SEQ-1 - l0 - st_) : (l0 + st_);                    \
            gload16(xin + ((size_t)t_*BATCH + b)*NIN + d*512 + hbase + ci8,     \
                    xb_ + j*1024);                                              \
        }                                                                       \
    }while(0)

#define RCOMP(base_, q_) do{                                                    \
        float u0[16],u1L[16],cs[16];                                            \
        _Pragma("unroll")                                                       \
        for (int i_=0;i_<16;i_++){                                              \
            u0[i_] = b2f(Ub[q_][(i_*3+0)*64+tid]);                              \
            u1L[i_]= fmaf(b2f(Ub[q_][(i_*3+1)*64+tid]), L2E, bfvL);             \
        }                                                                       \
        __builtin_amdgcn_sched_barrier(0);                                      \
        _Pragma("unroll")                                                       \
        for (int i_=0;i_<16;i_++){                                              \
            float e_ = exp2f(fmaf(-vfL, c, -u1L[i_]));                          \
            float f_ = __builtin_amdgcn_rcpf(1.f + e_);                         \
            c = fmaf(f_, c - u0[i_], u0[i_]);                                   \
            cs[i_] = c;                                                         \
        }                                                                       \
        __builtin_amdgcn_sched_barrier(0);                                      \
        _Pragma("unroll")                                                       \
        for (int i_=0;i_<16;i_++){                                              \
            int ss_=(base_)+i_;                                                 \
            int t_ = d ? (L_SEQ-1-l0-ss_) : (l0+ss_);                           \
            float u2L_ = fmaf(b2f(Ub[q_][(i_*3+2)*64+tid]), L2E, brvL);         \
            float xr_  = b2f(Xb[q_][i_*64+tid]);                                \
            float e2_ = exp2f(fmaf(-vrL, cs[i_], -u2L_));                       \
            float r_ = __builtin_amdgcn_rcpf(1.f + e2_);                        \
            xout[((size_t)t_*BATCH + b)*NIN + dcol] = f2b(fmaf(r_, cs[i_]-xr_, xr_)); \
        }                                                                       \
    }while(0)

    RSTAGE(0, 0);
    asm volatile("s_waitcnt vmcnt(0)" ::: "memory");
    __builtin_amdgcn_sched_barrier(0);
    int ngrp = C >> 4;
    for (int g = 0; g < ngrp; ++g){
        int q = g & 1;
        if (g + 1 < ngrp){
            RSTAGE((g+1)*16, q^1);                           // queue: L(g)8 | S(g-1)16 | L(g+1)8
            asm volatile("s_waitcnt vmcnt(24)" ::: "memory");// drain exactly L(g)
        } else {
            asm volatile("s_waitcnt vmcnt(16)" ::: "memory");// queue: L(g)8 | S(g-1)16
        }
        __builtin_amdgcn_sched_barrier(0);
        RCOMP(g*16, q);
    }
    carry[ch] = c;
#undef RSTAGE
#undef RCOMP
}

// ---------------- classifier: out[(b*L + l)*3 + j] = h[row l*8+b] @ Wcls + bcls
__global__ __launch_bounds__(256) void k_cls(const bf16* __restrict__ Xf, const float* __restrict__ Wc,
                                             const float* __restrict__ bc, float* __restrict__ out){
    int wave = threadIdx.x >> 6, lane = threadIdx.x & 63;
    int row = blockIdx.x*4 + wave;                  // row = l*8+b
    const bf16* xp = Xf + (size_t)row*NIN + lane*16;
    u16x8 v0 = *(const u16x8*)(xp);
    u16x8 v1 = *(const u16x8*)(xp + 8);
    float a0=0.f, a1=0.f, a2=0.f;
    #pragma unroll
    for (int i=0;i<16;i++){
        float xv = bits2f(i<8 ? v0[i&7] : v1[i&7]);
        int k = lane*16 + i;
        a0 += xv*Wc[k*3+0];
        a1 += xv*Wc[k*3+1];
        a2 += xv*Wc[k*3+2];
    }
    #pragma unroll
    for (int off=32; off; off>>=1){
        a0 += __shfl_down(a0, off);
        a1 += __shfl_down(a1, off);
        a2 += __shfl_down(a2, off);
    }
    if (lane == 0){
        int l = row >> 3, b = row & 7;
        float* op = out + ((size_t)b*L_SEQ + l)*3;
        op[0] = a0 + bc[0];
        op[1] = a1 + bc[1];
        op[2] = a2 + bc[2];
    }
}

// ----------------------------------------------------------------
extern "C" void kernel_launch(void* const* d_in, const int* in_sizes, int n_in,
                              void* d_out, int out_size, void* d_ws, size_t ws_size,
                              hipStream_t stream){
    (void)in_sizes; (void)n_in; (void)out_size;
    const float* X    = (const float*)d_in[0];
    const float* W[4]  = {(const float*)d_in[1],(const float*)d_in[4],(const float*)d_in[7],(const float*)d_in[10]};
    const float* wc[4] = {(const float*)d_in[2],(const float*)d_in[5],(const float*)d_in[8],(const float*)d_in[11]};
    const float* bb[4] = {(const float*)d_in[3],(const float*)d_in[6],(const float*)d_in[9],(const float*)d_in[12]};
    const float* Wcls = (const float*)d_in[13];
    const float* bcls = (const float*)d_in[14];
    float* out = (float*)d_out;

    // workspace layout:
    //   xA    bf16[16384*1024]  @ 0           33,554,432
    //   xB    bf16[16384*1024]  @ 33554432    33,554,432
    //   dxT   f32 [8*2048]      @ 67108864        65,536
    //   carry f32 [8192]        @ 67174400        32,768
    //   Wt0-2 bf16[3072*1024]   @ 67207168    3 x 6,291,456
    //   Ucb   bf16[C*2*8*1536]  @ 86081536    C*49,152   (C=2048 -> 100MB)
    char*  ws    = (char*)d_ws;
    bf16*  xA    = (bf16*)ws;
    bf16*  xB    = (bf16*)(ws + 33554432);
    float* dxT   = (float*)(ws + 67108864);
    float* carry = (float*)(ws + 67174400);
    bf16*  Wt[3] = {(bf16*)(ws + 67207168), (bf16*)(ws + 73498624), (bf16*)(ws + 79790080)};
    bf16*  Ucb   = (bf16*)(ws + 86081536);
    const size_t NEEDED = 86081536ull + 64ull*49152ull;

    if (ws_size < NEEDED){
        float code = 1.0e6f + (float)((ws_size >> 20) > 9999 ? 9999 : (ws_size >> 20)) * 100.0f;
        k_code<<<1, 64, 0, stream>>>(out, code);
        return;
    }

    int C = 2048;
    while (C > 64 && 86081536ull + (size_t)C*49152ull > ws_size) C >>= 1;

    k_diff  <<<(NROWS+255)/256, 256, 0, stream>>>(X, dxT);
    for (int i = 0; i < 3; ++i)
        k_wt<<<dim3(32,96), 256, 0, stream>>>(W[i+1], Wt[i]);
    k_layer0<<<32, 256, 0, stream>>>(dxT, W[0], wc[0], bb[0], xA);

    bf16* xin = xA; bf16* xo = xB;
    for (int layer = 1; layer < 4; ++layer){
        for (int l0 = 0; l0 < L_SEQ; l0 += C){
            dim3 g(C*8/128, NHALF/128, 2);
            k_gemm<<<g, 256, 0, stream>>>(xin, Wt[layer-1], Ucb, l0, C);
            k_rec <<<128, 64, 0, stream>>>(Ucb, xin, xo, carry, wc[layer], bb[layer], l0, C);
        }
        bf16* t = xin; xin = xo; xo = t;
    }
    k_cls<<<NROWS/4, 256, 0, stream>>>(xin, Wcls, bcls, out);
}

// Round 23
// 1205.754 us; speedup vs baseline: 1.4629x; 1.0988x over previous
//
#include <hip/hip_runtime.h>
#include <hip/hip_bf16.h>

typedef __hip_bfloat16 bf16;
typedef unsigned short u16x8 __attribute__((ext_vector_type(8)));
using v8s = __attribute__((ext_vector_type(8))) short;   // bf16 x8 MFMA frag (4 VGPR)
using v4f = __attribute__((ext_vector_type(4))) float;   // f32 x4 acc frag

#define L_SEQ 2048
#define BATCH 8
#define NIN   1024    // 2H
#define WLD   3072    // W row stride, layers 1-3
#define NHALF 1536    // per-direction columns (3*H)
#define NROWS (L_SEQ*BATCH)
#define L2E   1.4426950408889634f

__device__ __forceinline__ float bits2f(unsigned short u){ return __uint_as_float(((unsigned)u)<<16); }
__device__ __forceinline__ float b2f(bf16 v){ return __bfloat162float(v); }
__device__ __forceinline__ bf16  f2b(float v){ return __float2bfloat16(v); }

__device__ __forceinline__ void gload16(const void* g, void* l){
    __builtin_amdgcn_global_load_lds((const __attribute__((address_space(1))) void*)g,
                                     (__attribute__((address_space(3))) void*)l, 16, 0, 0);
}

__global__ void k_code(float* __restrict__ out, float v){
    if (threadIdx.x == 0 && blockIdx.x == 0) out[0] = v;
}

// ---------------- dxT[b][l] = X[b][l] - X[b][l-1], 0 at l=0  ((B,L) layout)
__global__ __launch_bounds__(256) void k_diff(const float* __restrict__ X, float* __restrict__ dxT){
    int i = blockIdx.x*256 + threadIdx.x;
    if (i >= NROWS) return;
    int l = i & (L_SEQ-1);
    float v = 0.f;
    if (l > 0) v = X[i] - X[i-1];
    dxT[i] = v;
}

// ---------------- W (fp32 [1024][3072]) -> Wt (bf16 [3072][1024], transposed)
__global__ __launch_bounds__(256) void k_wt(const float* __restrict__ W, bf16* __restrict__ Wt){
    __shared__ float t[32][33];
    int k0 = blockIdx.x*32, n0 = blockIdx.y*32;
    int tx = threadIdx.x & 31, ty = threadIdx.x >> 5;   // ty 0..7
    #pragma unroll
    for (int j=0;j<4;j++)
        t[ty*4+j][tx] = W[(size_t)(k0+ty*4+j)*WLD + n0 + tx];
    __syncthreads();
    #pragma unroll
    for (int j=0;j<4;j++)
        Wt[(size_t)(n0+ty*4+j)*NIN + k0 + tx] = f2b(t[tx][ty*4+j]);
}

// ---------------- layer 0: chain/post split (round-19/20 version)
__global__ __launch_bounds__(256) void k_layer0(const float* __restrict__ dxT, const float* __restrict__ W0,
                                                const float* __restrict__ wc, const float* __restrict__ bb,
                                                bf16* __restrict__ xout){
    __shared__ float sdx[L_SEQ];
    int g = blockIdx.x*256 + threadIdx.x;           // 8192 threads: (d,b,h); b,d block-uniform
    int h = g & 511, b = (g>>9) & 7, d = g >> 12;
    const float* dxp = dxT + b*L_SEQ;
    for (int t = threadIdx.x; t < L_SEQ; t += 256) sdx[t] = dxp[t];
    __syncthreads();

    int dcol = d*512 + h;
    float w0  = W0[d*2048 + h];
    float w1L = W0[d*2048 + 512 + h]*L2E;
    float w2L = W0[d*2048 + 1024 + h]*L2E;
    float w3  = W0[d*2048 + 1536 + h];
    float vfL = wc[dcol]*L2E,  vrL = wc[1024 + dcol]*L2E;
    float bfvL = bb[dcol]*L2E, brvL = bb[1024 + dcol]*L2E;
    float c = 0.f;

    int t0 = d ? (L_SEQ-1) : 0;
    bf16* xq = xout + ((size_t)t0*BATCH + b)*NIN + dcol;
    ptrdiff_t xs = d ? -(ptrdiff_t)(BATCH*NIN) : (ptrdiff_t)(BATCH*NIN);

#define LD0(P0,P1,P2,P3, s0) do{                                     \
        _Pragma("unroll")                                            \
        for (int i_=0;i_<8;i_++){                                    \
            int ss_ = (s0)+i_;                                       \
            float xv_ = sdx[d ? (L_SEQ-1-ss_) : ss_];                \
            P0[i_] = xv_*w0;                                         \
            P1[i_] = fmaf(xv_, w1L, bfvL);                           \
            P2[i_] = fmaf(xv_, w2L, brvL);                           \
            P3[i_] = xv_*w3;                                         \
        }                                                            \
        __builtin_amdgcn_sched_barrier(0);                           \
    }while(0)

#define STEP8(P0,P1,P2,P3) do{                                       \
        float cs_[8];                                                \
        _Pragma("unroll")                                            \
        for (int i_=0;i_<8;i_++){                                    \
            float e_ = exp2f(fmaf(-vfL, c, -P1[i_]));                \
            float f_ = __builtin_amdgcn_rcpf(1.f + e_);              \
            c = fmaf(f_, c - P0[i_], P0[i_]);                        \
            cs_[i_] = c;                                             \
        }                                                            \
        __builtin_amdgcn_sched_barrier(0);                           \
        _Pragma("unroll")                                            \
        for (int i_=0;i_<8;i_++){                                    \
            float e2_ = exp2f(fmaf(-vrL, cs_[i_], -P2[i_]));         \
            float r_ = __builtin_amdgcn_rcpf(1.f + e2_);             \
            xq[(ptrdiff_t)i_*xs] = f2b(fmaf(r_, cs_[i_]-P3[i_], P3[i_])); \
        }                                                            \
        xq += 8*xs;                                                  \
        __builtin_amdgcn_sched_barrier(0);                           \
    }while(0)

    float A0[8],A1[8],A2[8],A3[8], B0[8],B1[8],B2[8],B3[8];
    LD0(A0,A1,A2,A3, 0);
    for (int s0 = 0; s0 + 32 <= L_SEQ; s0 += 16){
        LD0(B0,B1,B2,B3, s0+8);
        STEP8(A0,A1,A2,A3);
        LD0(A0,A1,A2,A3, s0+16);
        STEP8(B0,B1,B2,B3);
    }
    LD0(B0,B1,B2,B3, L_SEQ-8);
    STEP8(A0,A1,A2,A3);
    STEP8(B0,B1,B2,B3);
#undef LD0
#undef STEP8
}

// ---------------- MFMA GEMM: UcH[set s] = x[all rows] @ Wt[set s]^T   (bf16 output, unchanged)
__global__ __launch_bounds__(256) void k_gemm(const bf16* __restrict__ Xin, const bf16* __restrict__ Wt,
                                              bf16* __restrict__ Uc, int l0, int C){
    __shared__ bf16 As[3][4096];   // [buf][128 m][32 k], 64B rows (8KB/buf)
    __shared__ bf16 Bs[3][4096];
    int tid = threadIdx.x;
    int lane = tid & 63;
    int s = blockIdx.z;
    int base = (s == 0) ? l0 : (L_SEQ - l0 - C);
    const bf16* A  = Xin + (size_t)base*BATCH*NIN;
    const bf16* Bm = Wt + (size_t)s*NHALF*NIN;
    bf16*       Cc = Uc + (size_t)s*(size_t)C*BATCH*NHALF;

    int m0 = blockIdx.x*128, n0 = blockIdx.y*128;
    int wv = tid >> 6;
    int wm = (wv >> 1)*64, wn = (wv & 1)*64;

    v4f acc[4][4];
    #pragma unroll
    for (int i=0;i<4;i++)
        #pragma unroll
        for (int j=0;j<4;j++)
            #pragma unroll
            for (int r=0;r<4;r++) acc[i][j][r] = 0.f;

    int row_a = tid >> 2;
    int kb = (((tid & 3) ^ ((tid >> 3) & 3)))*8;            // source-side swizzle
    int wbase = (tid & 192)*16;
    int fro = (lane & 15)*64 + (((lane >> 4) ^ (((lane & 15) >> 1) & 3)))*16;  // read-side swizzle

#define STAGE(q, k0) do{                                                        \
        char* la_ = (char*)As[0] + (q)*8192;                                    \
        char* lb_ = (char*)Bs[0] + (q)*8192;                                    \
        gload16(A  + (size_t)(m0 + row_a      )*NIN + (k0) + kb, la_ + wbase);  \
        gload16(A  + (size_t)(m0 + row_a + 64 )*NIN + (k0) + kb, la_ + 4096 + wbase); \
        gload16(Bm + (size_t)(n0 + row_a      )*NIN + (k0) + kb, lb_ + wbase);  \
        gload16(Bm + (size_t)(n0 + row_a + 64 )*NIN + (k0) + kb, lb_ + 4096 + wbase); \
    }while(0)

    STAGE(0, 0);
    STAGE(1, 32);
    int cur = 0;
    for (int it = 0; it < 32; ++it){
        if (it < 30){
            int nb = cur + 2; if (nb >= 3) nb -= 3;
            STAGE(nb, (it+2)*32);
            asm volatile("s_waitcnt vmcnt(8)" ::: "memory");   // drain tile-it (2 iters old)
        } else if (it == 30){
            asm volatile("s_waitcnt vmcnt(4)" ::: "memory");
        } else {
            asm volatile("s_waitcnt vmcnt(0)" ::: "memory");
        }
        __builtin_amdgcn_sched_barrier(0);
        __builtin_amdgcn_s_barrier();
        const char* la = (const char*)As[0] + cur*8192;
        const char* lb = (const char*)Bs[0] + cur*8192;
        v8s av[4], bv[4];
        #pragma unroll
        for (int i=0;i<4;i++) av[i] = *(const v8s*)(la + (wm + i*16)*64 + fro);
        #pragma unroll
        for (int j=0;j<4;j++) bv[j] = *(const v8s*)(lb + (wn + j*16)*64 + fro);
        #pragma unroll
        for (int i=0;i<4;i++)
            #pragma unroll
            for (int j=0;j<4;j++)
                acc[i][j] = __builtin_amdgcn_mfma_f32_16x16x32_bf16(av[i], bv[j], acc[i][j], 0, 0, 0);
        __builtin_amdgcn_s_barrier();
        cur = cur + 1; if (cur == 3) cur = 0;
    }
#undef STAGE

    int cr = (lane >> 4)*4, ccol = lane & 15;
    #pragma unroll
    for (int i=0;i<4;i++){
        #pragma unroll
        for (int j=0;j<4;j++){
            size_t rb = (size_t)(m0 + wm + i*16 + cr)*NHALF + (n0 + wn + j*16 + ccol);
            #pragma unroll
            for (int r=0;r<4;r++) Cc[rb + (size_t)r*NHALF] = f2b(acc[i][j][r]);
        }
    }
}

// ---------------- recurrence, layers 1-3: single-wave blocks, zero barriers, 16-step groups.
// ROUND 23: phase-A LDS reads forced via INLINE-ASM ds_read_u16 (32 back-to-back issues,
// single lgkmcnt(0) + sched_barrier fence) — regalloc cannot sink/remat asm outputs, so the
// serial chain runs register-only. One shared address VGPR; literal offset: immediates.
__global__ __launch_bounds__(64) void k_rec(const bf16* __restrict__ Uc, const bf16* __restrict__ xin,
                                            bf16* __restrict__ xout, float* __restrict__ carry,
                                            const float* __restrict__ wc, const float* __restrict__ bb,
                                            int l0, int C){
    __shared__ bf16 Ub[2][3072];    // [buf][seg=step*3+gate][64 bf16]  2x6KB
    __shared__ bf16 Xb[2][1024];    // [buf][step][64 bf16]             2x2KB
    int tid = threadIdx.x;          // 0..63
    int bid = blockIdx.x;           // 0..127
    int d = bid >> 6, b = (bid >> 3) & 7, hbase = (bid & 7)*64;
    int h = hbase + tid;
    int dcol = d*512 + h;
    int ch = d*4096 + b*512 + h;
    float vfL = wc[d*512 + h]*L2E, vrL = wc[1024 + d*512 + h]*L2E;
    float bfvL = bb[d*512 + h]*L2E, brvL = bb[1024 + d*512 + h]*L2E;
    float c = (l0 == 0) ? 0.f : carry[ch];

    const bf16* Ubase = Uc + (size_t)d*(size_t)C*12288 + b*1536 + hbase;   // row stride 12288 bf16
    int lo3 = tid >> 3, ci8 = (tid & 7)*8;   // seg-sublane split: 8 lanes x 16B per 128B seg

#define RSTAGE(base_, q_) do{                                                   \
        char* ub_ = (char*)Ub[q_]; char* xb_ = (char*)Xb[q_];                   \
        _Pragma("unroll")                                                       \
        for (int qq=0; qq<6; ++qq){                                             \
            int seg = qq*8 + lo3;                   /* 0..47 */                 \
            int st_ = seg/3, gate_ = seg - st_*3;                               \
            int ss_ = (base_) + st_;                                            \
            int row_ = d ? (C-1-ss_) : ss_;                                     \
            gload16(Ubase + (size_t)row_*12288 + gate_*512 + ci8,               \
                    ub_ + qq*1024);                                             \
        }                                                                       \
        _Pragma("unroll")                                                       \
        for (int j=0;j<2;++j){                                                  \
            int st_ = (base_) + j*8 + lo3;                                      \
            int t_  = d ? (L_SEQ-1 - l0 - st_) : (l0 + st_);                    \
            gload16(xin + ((size_t)t_*BATCH + b)*NIN + d*512 + hbase + ci8,     \
                    xb_ + j*1024);                                              \
        }                                                                       \
    }while(0)

// forced ds_read_u16: dst <- LDS[ab + byte-offset], offset literal (seg*128; u0: i*384, u1: +128)
#define DSR(dst, o) asm volatile("ds_read_u16 %0, %1 offset:" #o : "=v"(dst) : "v"(ab))

#define RCOMP(base_, q_) do{                                                    \
        unsigned ab = (unsigned)(size_t)&Ub[q_][tid];                           \
        unsigned t0_[16], t1_[16];                                              \
        DSR(t0_[0] ,0);    DSR(t1_[0] ,128);                                    \
        DSR(t0_[1] ,384);  DSR(t1_[1] ,512);                                    \
        DSR(t0_[2] ,768);  DSR(t1_[2] ,896);                                    \
        DSR(t0_[3] ,1152); DSR(t1_[3] ,1280);                                   \
        DSR(t0_[4] ,1536); DSR(t1_[4] ,1664);                                   \
        DSR(t0_[5] ,1920); DSR(t1_[5] ,2048);                                   \
        DSR(t0_[6] ,2304); DSR(t1_[6] ,2432);                                   \
        DSR(t0_[7] ,2688); DSR(t1_[7] ,2816);                                   \
        DSR(t0_[8] ,3072); DSR(t1_[8] ,3200);                                   \
        DSR(t0_[9] ,3456); DSR(t1_[9] ,3584);                                   \
        DSR(t0_[10],3840); DSR(t1_[10],3968);                                   \
        DSR(t0_[11],4224); DSR(t1_[11],4352);                                   \
        DSR(t0_[12],4608); DSR(t1_[12],4736);                                   \
        DSR(t0_[13],4992); DSR(t1_[13],5120);                                   \
        DSR(t0_[14],5376); DSR(t1_[14],5504);                                   \
        DSR(t0_[15],5760); DSR(t1_[15],5888);                                   \
        asm volatile("s_waitcnt lgkmcnt(0)" ::: "memory");                      \
        __builtin_amdgcn_sched_barrier(0);                                      \
        float cs[16];                                                           \
        _Pragma("unroll")                                                       \
        for (int i_=0;i_<16;i_++){                                              \
            float u0_ = __uint_as_float(t0_[i_]<<16);                           \
            float u1L_= fmaf(__uint_as_float(t1_[i_]<<16), L2E, bfvL);          \
            float e_ = exp2f(fmaf(-vfL, c, -u1L_));                             \
            float f_ = __builtin_amdgcn_rcpf(1.f + e_);                         \
            c = fmaf(f_, c - u0_, u0_);                                         \
            cs[i_] = c;                                                         \
        }                                                                       \
        __builtin_amdgcn_sched_barrier(0);                                      \
        _Pragma("unroll")                                                       \
        for (int i_=0;i_<16;i_++){                                              \
            int ss_=(base_)+i_;                                                 \
            int t_ = d ? (L_SEQ-1-l0-ss_) : (l0+ss_);                           \
            float u2L_ = fmaf(b2f(Ub[q_][(i_*3+2)*64+tid]), L2E, brvL);         \
            float xr_  = b2f(Xb[q_][i_*64+tid]);                                \
            float e2_ = exp2f(fmaf(-vrL, cs[i_], -u2L_));                       \
            float r_ = __builtin_amdgcn_rcpf(1.f + e2_);                        \
            xout[((size_t)t_*BATCH + b)*NIN + dcol] = f2b(fmaf(r_, cs[i_]-xr_, xr_)); \
        }                                                                       \
    }while(0)

    RSTAGE(0, 0);
    asm volatile("s_waitcnt vmcnt(0)" ::: "memory");
    __builtin_amdgcn_sched_barrier(0);
    int ngrp = C >> 4;
    for (int g = 0; g < ngrp; ++g){
        int q = g & 1;
        if (g + 1 < ngrp){
            RSTAGE((g+1)*16, q^1);                           // queue: L(g)8 | S(g-1)16 | L(g+1)8
            asm volatile("s_waitcnt vmcnt(24)" ::: "memory");// drain exactly L(g)
        } else {
            asm volatile("s_waitcnt vmcnt(16)" ::: "memory");// queue: L(g)8 | S(g-1)16
        }
        __builtin_amdgcn_sched_barrier(0);
        RCOMP(g*16, q);
    }
    carry[ch] = c;
#undef RSTAGE
#undef RCOMP
#undef DSR
}

// ---------------- classifier: out[(b*L + l)*3 + j] = h[row l*8+b] @ Wcls + bcls
__global__ __launch_bounds__(256) void k_cls(const bf16* __restrict__ Xf, const float* __restrict__ Wc,
                                             const float* __restrict__ bc, float* __restrict__ out){
    int wave = threadIdx.x >> 6, lane = threadIdx.x & 63;
    int row = blockIdx.x*4 + wave;                  // row = l*8+b
    const bf16* xp = Xf + (size_t)row*NIN + lane*16;
    u16x8 v0 = *(const u16x8*)(xp);
    u16x8 v1 = *(const u16x8*)(xp + 8);
    float a0=0.f, a1=0.f, a2=0.f;
    #pragma unroll
    for (int i=0;i<16;i++){
        float xv = bits2f(i<8 ? v0[i&7] : v1[i&7]);
        int k = lane*16 + i;
        a0 += xv*Wc[k*3+0];
        a1 += xv*Wc[k*3+1];
        a2 += xv*Wc[k*3+2];
    }
    #pragma unroll
    for (int off=32; off; off>>=1){
        a0 += __shfl_down(a0, off);
        a1 += __shfl_down(a1, off);
        a2 += __shfl_down(a2, off);
    }
    if (lane == 0){
        int l = row >> 3, b = row & 7;
        float* op = out + ((size_t)b*L_SEQ + l)*3;
        op[0] = a0 + bc[0];
        op[1] = a1 + bc[1];
        op[2] = a2 + bc[2];
    }
}

// ----------------------------------------------------------------
extern "C" void kernel_launch(void* const* d_in, const int* in_sizes, int n_in,
                              void* d_out, int out_size, void* d_ws, size_t ws_size,
                              hipStream_t stream){
    (void)in_sizes; (void)n_in; (void)out_size;
    const float* X    = (const float*)d_in[0];
    const float* W[4]  = {(const float*)d_in[1],(const float*)d_in[4],(const float*)d_in[7],(const float*)d_in[10]};
    const float* wc[4] = {(const float*)d_in[2],(const float*)d_in[5],(const float*)d_in[8],(const float*)d_in[11]};
    const float* bb[4] = {(const float*)d_in[3],(const float*)d_in[6],(const float*)d_in[9],(const float*)d_in[12]};
    const float* Wcls = (const float*)d_in[13];
    const float* bcls = (const float*)d_in[14];
    float* out = (float*)d_out;

    // workspace layout:
    //   xA    bf16[16384*1024]  @ 0           33,554,432
    //   xB    bf16[16384*1024]  @ 33554432    33,554,432
    //   dxT   f32 [8*2048]      @ 67108864        65,536
    //   carry f32 [8192]        @ 67174400        32,768
    //   Wt0-2 bf16[3072*1024]   @ 67207168    3 x 6,291,456
    //   Ucb   bf16[C*2*8*1536]  @ 86081536    C*49,152   (C=2048 -> 100MB)
    char*  ws    = (char*)d_ws;
    bf16*  xA    = (bf16*)ws;
    bf16*  xB    = (bf16*)(ws + 33554432);
    float* dxT   = (float*)(ws + 67108864);
    float* carry = (float*)(ws + 67174400);
    bf16*  Wt[3] = {(bf16*)(ws + 67207168), (bf16*)(ws + 73498624), (bf16*)(ws + 79790080)};
    bf16*  Ucb   = (bf16*)(ws + 86081536);
    const size_t NEEDED = 86081536ull + 64ull*49152ull;

    if (ws_size < NEEDED){
        float code = 1.0e6f + (float)((ws_size >> 20) > 9999 ? 9999 : (ws_size >> 20)) * 100.0f;
        k_code<<<1, 64, 0, stream>>>(out, code);
        return;
    }

    int C = 2048;
    while (C > 64 && 86081536ull + (size_t)C*49152ull > ws_size) C >>= 1;

    k_diff  <<<(NROWS+255)/256, 256, 0, stream>>>(X, dxT);
    for (int i = 0; i < 3; ++i)
        k_wt<<<dim3(32,96), 256, 0, stream>>>(W[i+1], Wt[i]);
    k_layer0<<<32, 256, 0, stream>>>(dxT, W[0], wc[0], bb[0], xA);

    bf16* xin = xA; bf16* xo = xB;
    for (int layer = 1; layer < 4; ++layer){
        for (int l0 = 0; l0 < L_SEQ; l0 += C){
            dim3 g(C*8/128, NHALF/128, 2);
            k_gemm<<<g, 256, 0, stream>>>(xin, Wt[layer-1], Ucb, l0, C);
            k_rec <<<128, 64, 0, stream>>>(Ucb, xin, xo, carry, wc[layer], bb[layer], l0, C);
        }
        bf16* t = xin; xin = xo; xo = t;
    }
    k_cls<<<NROWS/4, 256, 0, stream>>>(xin, Wcls, bcls, out);
}

// Round 24
// 1015.926 us; speedup vs baseline: 1.7363x; 1.1869x over previous
//
#include <hip/hip_runtime.h>
#include <hip/hip_bf16.h>

typedef __hip_bfloat16 bf16;
typedef unsigned short u16x8 __attribute__((ext_vector_type(8)));
using v8s = __attribute__((ext_vector_type(8))) short;   // bf16 x8 MFMA frag (4 VGPR)
using v4f = __attribute__((ext_vector_type(4))) float;   // f32 x4 acc frag

#define L_SEQ 2048
#define BATCH 8
#define NIN   1024    // 2H
#define WLD   3072    // W row stride, layers 1-3
#define NHALF 1536    // per-direction columns (3*H)
#define NROWS (L_SEQ*BATCH)
#define L2E   1.4426950408889634f

__device__ __forceinline__ float bits2f(unsigned short u){ return __uint_as_float(((unsigned)u)<<16); }
__device__ __forceinline__ float b2f(bf16 v){ return __bfloat162float(v); }
__device__ __forceinline__ bf16  f2b(float v){ return __float2bfloat16(v); }

__device__ __forceinline__ void gload16(const void* g, void* l){
    __builtin_amdgcn_global_load_lds((const __attribute__((address_space(1))) void*)g,
                                     (__attribute__((address_space(3))) void*)l, 16, 0, 0);
}

__global__ void k_code(float* __restrict__ out, float v){
    if (threadIdx.x == 0 && blockIdx.x == 0) out[0] = v;
}

// ---------------- dxT[b][l] = X[b][l] - X[b][l-1], 0 at l=0  ((B,L) layout)
__global__ __launch_bounds__(256) void k_diff(const float* __restrict__ X, float* __restrict__ dxT){
    int i = blockIdx.x*256 + threadIdx.x;
    if (i >= NROWS) return;
    int l = i & (L_SEQ-1);
    float v = 0.f;
    if (l > 0) v = X[i] - X[i-1];
    dxT[i] = v;
}

// ---------------- W (fp32 [1024][3072]) -> Wt (bf16 [3072][1024], transposed)
__global__ __launch_bounds__(256) void k_wt(const float* __restrict__ W, bf16* __restrict__ Wt){
    __shared__ float t[32][33];
    int k0 = blockIdx.x*32, n0 = blockIdx.y*32;
    int tx = threadIdx.x & 31, ty = threadIdx.x >> 5;   // ty 0..7
    #pragma unroll
    for (int j=0;j<4;j++)
        t[ty*4+j][tx] = W[(size_t)(k0+ty*4+j)*WLD + n0 + tx];
    __syncthreads();
    #pragma unroll
    for (int j=0;j<4;j++)
        Wt[(size_t)(n0+ty*4+j)*NIN + k0 + tx] = f2b(t[tx][ty*4+j]);
}

// ---------------- layer 0: chain/post split (round-19/20 version)
__global__ __launch_bounds__(256) void k_layer0(const float* __restrict__ dxT, const float* __restrict__ W0,
                                                const float* __restrict__ wc, const float* __restrict__ bb,
                                                bf16* __restrict__ xout){
    __shared__ float sdx[L_SEQ];
    int g = blockIdx.x*256 + threadIdx.x;           // 8192 threads: (d,b,h); b,d block-uniform
    int h = g & 511, b = (g>>9) & 7, d = g >> 12;
    const float* dxp = dxT + b*L_SEQ;
    for (int t = threadIdx.x; t < L_SEQ; t += 256) sdx[t] = dxp[t];
    __syncthreads();

    int dcol = d*512 + h;
    float w0  = W0[d*2048 + h];
    float w1L = W0[d*2048 + 512 + h]*L2E;
    float w2L = W0[d*2048 + 1024 + h]*L2E;
    float w3  = W0[d*2048 + 1536 + h];
    float vfL = wc[dcol]*L2E,  vrL = wc[1024 + dcol]*L2E;
    float bfvL = bb[dcol]*L2E, brvL = bb[1024 + dcol]*L2E;
    float c = 0.f;

    int t0 = d ? (L_SEQ-1) : 0;
    bf16* xq = xout + ((size_t)t0*BATCH + b)*NIN + dcol;
    ptrdiff_t xs = d ? -(ptrdiff_t)(BATCH*NIN) : (ptrdiff_t)(BATCH*NIN);

#define LD0(P0,P1,P2,P3, s0) do{                                     \
        _Pragma("unroll")                                            \
        for (int i_=0;i_<8;i_++){                                    \
            int ss_ = (s0)+i_;                                       \
            float xv_ = sdx[d ? (L_SEQ-1-ss_) : ss_];                \
            P0[i_] = xv_*w0;                                         \
            P1[i_] = fmaf(xv_, w1L, bfvL);                           \
            P2[i_] = fmaf(xv_, w2L, brvL);                           \
            P3[i_] = xv_*w3;                                         \
        }                                                            \
        __builtin_amdgcn_sched_barrier(0);                           \
    }while(0)

#define STEP8(P0,P1,P2,P3) do{                                       \
        float cs_[8];                                                \
        _Pragma("unroll")                                            \
        for (int i_=0;i_<8;i_++){                                    \
            float e_ = exp2f(fmaf(-vfL, c, -P1[i_]));                \
            float f_ = __builtin_amdgcn_rcpf(1.f + e_);              \
            c = fmaf(f_, c - P0[i_], P0[i_]);                        \
            cs_[i_] = c;                                             \
        }                                                            \
        __builtin_amdgcn_sched_barrier(0);                           \
        _Pragma("unroll")                                            \
        for (int i_=0;i_<8;i_++){                                    \
            float e2_ = exp2f(fmaf(-vrL, cs_[i_], -P2[i_]));         \
            float r_ = __builtin_amdgcn_rcpf(1.f + e2_);             \
            xq[(ptrdiff_t)i_*xs] = f2b(fmaf(r_, cs_[i_]-P3[i_], P3[i_])); \
        }                                                            \
        xq += 8*xs;                                                  \
        __builtin_amdgcn_sched_barrier(0);                           \
    }while(0)

    float A0[8],A1[8],A2[8],A3[8], B0[8],B1[8],B2[8],B3[8];
    LD0(A0,A1,A2,A3, 0);
    for (int s0 = 0; s0 + 32 <= L_SEQ; s0 += 16){
        LD0(B0,B1,B2,B3, s0+8);
        STEP8(A0,A1,A2,A3);
        LD0(A0,A1,A2,A3, s0+16);
        STEP8(B0,B1,B2,B3);
    }
    LD0(B0,B1,B2,B3, L_SEQ-8);
    STEP8(A0,A1,A2,A3);
    STEP8(B0,B1,B2,B3);
#undef LD0
#undef STEP8
}

// ---------------- MFMA GEMM: UcH[set s] = x[all rows] @ Wt[set s]^T   (bf16 output, unchanged)
__global__ __launch_bounds__(256) void k_gemm(const bf16* __restrict__ Xin, const bf16* __restrict__ Wt,
                                              bf16* __restrict__ Uc, int l0, int C){
    __shared__ bf16 As[3][4096];   // [buf][128 m][32 k], 64B rows (8KB/buf)
    __shared__ bf16 Bs[3][4096];
    int tid = threadIdx.x;
    int lane = tid & 63;
    int s = blockIdx.z;
    int base = (s == 0) ? l0 : (L_SEQ - l0 - C);
    const bf16* A  = Xin + (size_t)base*BATCH*NIN;
    const bf16* Bm = Wt + (size_t)s*NHALF*NIN;
    bf16*       Cc = Uc + (size_t)s*(size_t)C*BATCH*NHALF;

    int m0 = blockIdx.x*128, n0 = blockIdx.y*128;
    int wv = tid >> 6;
    int wm = (wv >> 1)*64, wn = (wv & 1)*64;

    v4f acc[4][4];
    #pragma unroll
    for (int i=0;i<4;i++)
        #pragma unroll
        for (int j=0;j<4;j++)
            #pragma unroll
            for (int r=0;r<4;r++) acc[i][j][r] = 0.f;

    int row_a = tid >> 2;
    int kb = (((tid & 3) ^ ((tid >> 3) & 3)))*8;            // source-side swizzle
    int wbase = (tid & 192)*16;
    int fro = (lane & 15)*64 + (((lane >> 4) ^ (((lane & 15) >> 1) & 3)))*16;  // read-side swizzle

#define STAGE(q, k0) do{                                                        \
        char* la_ = (char*)As[0] + (q)*8192;                                    \
        char* lb_ = (char*)Bs[0] + (q)*8192;                                    \
        gload16(A  + (size_t)(m0 + row_a      )*NIN + (k0) + kb, la_ + wbase);  \
        gload16(A  + (size_t)(m0 + row_a + 64 )*NIN + (k0) + kb, la_ + 4096 + wbase); \
        gload16(Bm + (size_t)(n0 + row_a      )*NIN + (k0) + kb, lb_ + wbase);  \
        gload16(Bm + (size_t)(n0 + row_a + 64 )*NIN + (k0) + kb, lb_ + 4096 + wbase); \
    }while(0)

    STAGE(0, 0);
    STAGE(1, 32);
    int cur = 0;
    for (int it = 0; it < 32; ++it){
        if (it < 30){
            int nb = cur + 2; if (nb >= 3) nb -= 3;
            STAGE(nb, (it+2)*32);
            asm volatile("s_waitcnt vmcnt(8)" ::: "memory");   // drain tile-it (2 iters old)
        } else if (it == 30){
            asm volatile("s_waitcnt vmcnt(4)" ::: "memory");
        } else {
            asm volatile("s_waitcnt vmcnt(0)" ::: "memory");
        }
        __builtin_amdgcn_sched_barrier(0);
        __builtin_amdgcn_s_barrier();
        const char* la = (const char*)As[0] + cur*8192;
        const char* lb = (const char*)Bs[0] + cur*8192;
        v8s av[4], bv[4];
        #pragma unroll
        for (int i=0;i<4;i++) av[i] = *(const v8s*)(la + (wm + i*16)*64 + fro);
        #pragma unroll
        for (int j=0;j<4;j++) bv[j] = *(const v8s*)(lb + (wn + j*16)*64 + fro);
        #pragma unroll
        for (int i=0;i<4;i++)
            #pragma unroll
            for (int j=0;j<4;j++)
                acc[i][j] = __builtin_amdgcn_mfma_f32_16x16x32_bf16(av[i], bv[j], acc[i][j], 0, 0, 0);
        __builtin_amdgcn_s_barrier();
        cur = cur + 1; if (cur == 3) cur = 0;
    }
#undef STAGE

    int cr = (lane >> 4)*4, ccol = lane & 15;
    #pragma unroll
    for (int i=0;i<4;i++){
        #pragma unroll
        for (int j=0;j<4;j++){
            size_t rb = (size_t)(m0 + wm + i*16 + cr)*NHALF + (n0 + wn + j*16 + ccol);
            #pragma unroll
            for (int r=0;r<4;r++) Cc[rb + (size_t)r*NHALF] = f2b(acc[i][j][r]);
        }
    }
}

// ---------------- recurrence, layers 1-3: PRODUCER/CONSUMER WAVE SPECIALIZATION.
// 128 blocks x 128 threads (2 waves). Wave0 = serial f-gate chain (asm ds_reads, writes cs
// to LDS). Wave1 = post of group g-1 (r-sigmoid/blend/stores) + X staging. The waves run on
// different SIMDs concurrently. Triple-buffer U/X (stage g+1 | chain g | post g-1); 2-buffer cs.
// Per-wave vmcnt: w0 steady (3); w1 (5) for g<2 (no stores outstanding), (21) steady, (16) tail.
__global__ __launch_bounds__(128) void k_rec(const bf16* __restrict__ Uc, const bf16* __restrict__ xin,
                                             bf16* __restrict__ xout, float* __restrict__ carry,
                                             const float* __restrict__ wc, const float* __restrict__ bb,
                                             int l0, int C){
    __shared__ bf16  Ub[3][3072];   // [buf][seg=step*3+gate][64 bf16]  3x6KB
    __shared__ bf16  Xb[3][1024];   // [buf][step][64 bf16]             3x2KB
    __shared__ float csb[2][1024];  // [buf][step][64 f32]              2x4KB
    int tid = threadIdx.x;
    int wv = tid >> 6, lane = tid & 63;
    int bid = blockIdx.x;           // 0..127
    int d = bid >> 6, b = (bid >> 3) & 7, hbase = (bid & 7)*64;
    int h = hbase + lane;
    int dcol = d*512 + h;
    int ch = d*4096 + b*512 + h;
    float vfL = wc[d*512 + h]*L2E, vrL = wc[1024 + d*512 + h]*L2E;
    float bfvL = bb[d*512 + h]*L2E, brvL = bb[1024 + d*512 + h]*L2E;
    float c = (l0 == 0) ? 0.f : carry[ch];

    const bf16* Ubase = Uc + (size_t)d*(size_t)C*12288 + b*1536 + hbase;   // row stride 12288 bf16
    int lo3 = lane >> 3, ci8 = (lane & 7)*8;
    int ngrp = C >> 4;

#define RST_W0(base_, q_) do{                                                   \
        char* ub_ = (char*)Ub[q_];                                              \
        _Pragma("unroll")                                                       \
        for (int qq=0; qq<3; ++qq){                                             \
            int seg = qq*8 + lo3;                                               \
            int st_ = seg/3, gate_ = seg - st_*3;                               \
            int ss_ = (base_) + st_;                                            \
            int row_ = d ? (C-1-ss_) : ss_;                                     \
            gload16(Ubase + (size_t)row_*12288 + gate_*512 + ci8,               \
                    ub_ + qq*1024);                                             \
        }                                                                       \
    }while(0)

#define RST_W1(base_, q_) do{                                                   \
        char* ub_ = (char*)Ub[q_]; char* xb_ = (char*)Xb[q_];                   \
        _Pragma("unroll")                                                       \
        for (int qq=3; qq<6; ++qq){                                             \
            int seg = qq*8 + lo3;                                               \
            int st_ = seg/3, gate_ = seg - st_*3;                               \
            int ss_ = (base_) + st_;                                            \
            int row_ = d ? (C-1-ss_) : ss_;                                     \
            gload16(Ubase + (size_t)row_*12288 + gate_*512 + ci8,               \
                    ub_ + qq*1024);                                             \
        }                                                                       \
        _Pragma("unroll")                                                       \
        for (int j=0;j<2;++j){                                                  \
            int st_ = (base_) + j*8 + lo3;                                      \
            int t_  = d ? (L_SEQ-1 - l0 - st_) : (l0 + st_);                    \
            gload16(xin + ((size_t)t_*BATCH + b)*NIN + d*512 + hbase + ci8,     \
                    xb_ + j*1024);                                              \
        }                                                                       \
    }while(0)

#define DSR(dst, o) asm volatile("ds_read_u16 %0, %1 offset:" #o : "=v"(dst) : "v"(ab))

#define CHAIN(q_, qc_) do{                                                      \
        unsigned ab = (unsigned)(size_t)&Ub[q_][lane];                          \
        unsigned t0_[16], t1_[16];                                              \
        DSR(t0_[0] ,0);    DSR(t1_[0] ,128);                                    \
        DSR(t0_[1] ,384);  DSR(t1_[1] ,512);                                    \
        DSR(t0_[2] ,768);  DSR(t1_[2] ,896);                                    \
        DSR(t0_[3] ,1152); DSR(t1_[3] ,1280);                                   \
        DSR(t0_[4] ,1536); DSR(t1_[4] ,1664);                                   \
        DSR(t0_[5] ,1920); DSR(t1_[5] ,2048);                                   \
        DSR(t0_[6] ,2304); DSR(t1_[6] ,2432);                                   \
        DSR(t0_[7] ,2688); DSR(t1_[7] ,2816);                                   \
        DSR(t0_[8] ,3072); DSR(t1_[8] ,3200);                                   \
        DSR(t0_[9] ,3456); DSR(t1_[9] ,3584);                                   \
        DSR(t0_[10],3840); DSR(t1_[10],3968);                                   \
        DSR(t0_[11],4224); DSR(t1_[11],4352);                                   \
        DSR(t0_[12],4608); DSR(t1_[12],4736);                                   \
        DSR(t0_[13],4992); DSR(t1_[13],5120);                                   \
        DSR(t0_[14],5376); DSR(t1_[14],5504);                                   \
        DSR(t0_[15],5760); DSR(t1_[15],5888);                                   \
        asm volatile("s_waitcnt lgkmcnt(0)" ::: "memory");                      \
        __builtin_amdgcn_sched_barrier(0);                                      \
        _Pragma("unroll")                                                       \
        for (int i_=0;i_<16;i_++){                                              \
            float u0_ = __uint_as_float(t0_[i_]<<16);                           \
            float u1L_= fmaf(__uint_as_float(t1_[i_]<<16), L2E, bfvL);          \
            float e_ = exp2f(fmaf(-vfL, c, -u1L_));                             \
            float f_ = __builtin_amdgcn_rcpf(1.f + e_);                         \
            c = fmaf(f_, c - u0_, u0_);                                         \
            csb[qc_][i_*64 + lane] = c;                                         \
        }                                                                       \
    }while(0)

#define POST(gp_, qp_, qcp_) do{                                                \
        bf16* xq_ = xout + ((size_t)(d ? (L_SEQ-1 - l0 - (gp_)*16) : (l0 + (gp_)*16))*BATCH + b)*NIN + dcol; \
        ptrdiff_t xs_ = d ? -(ptrdiff_t)(BATCH*NIN) : (ptrdiff_t)(BATCH*NIN);   \
        _Pragma("unroll")                                                       \
        for (int i_=0;i_<16;i_++){                                              \
            float cs_ = csb[qcp_][i_*64 + lane];                                \
            float u2L_ = fmaf(b2f(Ub[qp_][(i_*3+2)*64 + lane]), L2E, brvL);     \
            float xr_  = b2f(Xb[qp_][i_*64 + lane]);                            \
            float e2_ = exp2f(fmaf(-vrL, cs_, -u2L_));                          \
            float r_ = __builtin_amdgcn_rcpf(1.f + e2_);                        \
            xq_[(ptrdiff_t)i_*xs_] = f2b(fmaf(r_, cs_-xr_, xr_));               \
        }                                                                       \
    }while(0)

    if (wv == 0) RST_W0(0, 0); else RST_W1(0, 0);
    asm volatile("s_waitcnt vmcnt(0)" ::: "memory");
    __builtin_amdgcn_sched_barrier(0);
    __builtin_amdgcn_s_barrier();

    int q0 = 0;
    for (int g = 0; g < ngrp; ++g){
        int qn = q0 + 1; if (qn == 3) qn = 0;
        if (g + 1 < ngrp){
            if (wv == 0){
                RST_W0((g+1)*16, qn);
                asm volatile("s_waitcnt vmcnt(3)" ::: "memory");     // drain L(g): newer = L(g+1)3
            } else {
                RST_W1((g+1)*16, qn);
                if (g < 2) asm volatile("s_waitcnt vmcnt(5)" ::: "memory");   // no stores yet
                else       asm volatile("s_waitcnt vmcnt(21)" ::: "memory");  // newer = S16 + L(g+1)5
            }
        } else {
            if (wv == 0) asm volatile("s_waitcnt vmcnt(0)" ::: "memory");
            else         asm volatile("s_waitcnt vmcnt(16)" ::: "memory");    // newer = S16
        }
        __builtin_amdgcn_sched_barrier(0);
        __builtin_amdgcn_s_barrier();        // Ub/Xb[g] resident (both staging halves)

        if (wv == 0){
            CHAIN(q0, g & 1);
        } else if (g > 0){
            int qp = q0 + 2; if (qp >= 3) qp -= 3;     // buffer of group g-1
            POST(g-1, qp, (g-1) & 1);
        }
        __builtin_amdgcn_sched_barrier(0);
        asm volatile("s_waitcnt lgkmcnt(0)" ::: "memory");   // cs writes visible; LDS reads done
        __builtin_amdgcn_sched_barrier(0);
        __builtin_amdgcn_s_barrier();        // orders cs(g) vs read(g+1); post(g-1) vs restage
        q0 = qn;
    }
    if (wv == 1){
        int qp = q0 + 2; if (qp >= 3) qp -= 3;         // buffer of group ngrp-1
        POST(ngrp-1, qp, (ngrp-1) & 1);
    } else {
        carry[ch] = c;
    }
#undef RST_W0
#undef RST_W1
#undef CHAIN
#undef POST
#undef DSR
}

// ---------------- classifier: out[(b*L + l)*3 + j] = h[row l*8+b] @ Wcls + bcls
__global__ __launch_bounds__(256) void k_cls(const bf16* __restrict__ Xf, const float* __restrict__ Wc,
                                             const float* __restrict__ bc, float* __restrict__ out){
    int wave = threadIdx.x >> 6, lane = threadIdx.x & 63;
    int row = blockIdx.x*4 + wave;                  // row = l*8+b
    const bf16* xp = Xf + (size_t)row*NIN + lane*16;
    u16x8 v0 = *(const u16x8*)(xp);
    u16x8 v1 = *(const u16x8*)(xp + 8);
    float a0=0.f, a1=0.f, a2=0.f;
    #pragma unroll
    for (int i=0;i<16;i++){
        float xv = bits2f(i<8 ? v0[i&7] : v1[i&7]);
        int k = lane*16 + i;
        a0 += xv*Wc[k*3+0];
        a1 += xv*Wc[k*3+1];
        a2 += xv*Wc[k*3+2];
    }
    #pragma unroll
    for (int off=32; off; off>>=1){
        a0 += __shfl_down(a0, off);
        a1 += __shfl_down(a1, off);
        a2 += __shfl_down(a2, off);
    }
    if (lane == 0){
        int l = row >> 3, b = row & 7;
        float* op = out + ((size_t)b*L_SEQ + l)*3;
        op[0] = a0 + bc[0];
        op[1] = a1 + bc[1];
        op[2] = a2 + bc[2];
    }
}

// ----------------------------------------------------------------
extern "C" void kernel_launch(void* const* d_in, const int* in_sizes, int n_in,
                              void* d_out, int out_size, void* d_ws, size_t ws_size,
                              hipStream_t stream){
    (void)in_sizes; (void)n_in; (void)out_size;
    const float* X    = (const float*)d_in[0];
    const float* W[4]  = {(const float*)d_in[1],(const float*)d_in[4],(const float*)d_in[7],(const float*)d_in[10]};
    const float* wc[4] = {(const float*)d_in[2],(const float*)d_in[5],(const float*)d_in[8],(const float*)d_in[11]};
    const float* bb[4] = {(const float*)d_in[3],(const float*)d_in[6],(const float*)d_in[9],(const float*)d_in[12]};
    const float* Wcls = (const float*)d_in[13];
    const float* bcls = (const float*)d_in[14];
    float* out = (float*)d_out;

    // workspace layout:
    //   xA    bf16[16384*1024]  @ 0           33,554,432
    //   xB    bf16[16384*1024]  @ 33554432    33,554,432
    //   dxT   f32 [8*2048]      @ 67108864        65,536
    //   carry f32 [8192]        @ 67174400        32,768
    //   Wt0-2 bf16[3072*1024]   @ 67207168    3 x 6,291,456
    //   Ucb   bf16[C*2*8*1536]  @ 86081536    C*49,152   (C=2048 -> 100MB)
    char*  ws    = (char*)d_ws;
    bf16*  xA    = (bf16*)ws;
    bf16*  xB    = (bf16*)(ws + 33554432);
    float* dxT   = (float*)(ws + 67108864);
    float* carry = (float*)(ws + 67174400);
    bf16*  Wt[3] = {(bf16*)(ws + 67207168), (bf16*)(ws + 73498624), (bf16*)(ws + 79790080)};
    bf16*  Ucb   = (bf16*)(ws + 86081536);
    const size_t NEEDED = 86081536ull + 64ull*49152ull;

    if (ws_size < NEEDED){
        float code = 1.0e6f + (float)((ws_size >> 20) > 9999 ? 9999 : (ws_size >> 20)) * 100.0f;
        k_code<<<1, 64, 0, stream>>>(out, code);
        return;
    }

    int C = 2048;
    while (C > 64 && 86081536ull + (size_t)C*49152ull > ws_size) C >>= 1;

    k_diff  <<<(NROWS+255)/256, 256, 0, stream>>>(X, dxT);
    for (int i = 0; i < 3; ++i)
        k_wt<<<dim3(32,96), 256, 0, stream>>>(W[i+1], Wt[i]);
    k_layer0<<<32, 256, 0, stream>>>(dxT, W[0], wc[0], bb[0], xA);

    bf16* xin = xA; bf16* xo = xB;
    for (int layer = 1; layer < 4; ++layer){
        for (int l0 = 0; l0 < L_SEQ; l0 += C){
            dim3 g(C*8/128, NHALF/128, 2);
            k_gemm<<<g, 256, 0, stream>>>(xin, Wt[layer-1], Ucb, l0, C);
            k_rec <<<128, 128, 0, stream>>>(Ucb, xin, xo, carry, wc[layer], bb[layer], l0, C);
        }
        bf16* t = xin; xin = xo; xo = t;
    }
    k_cls<<<NROWS/4, 256, 0, stream>>>(xin, Wcls, bcls, out);
}

// Round 25
// 960.147 us; speedup vs baseline: 1.8371x; 1.0581x over previous
//
#include <hip/hip_runtime.h>
#include <hip/hip_bf16.h>

typedef __hip_bfloat16 bf16;
typedef unsigned short u16x8 __attribute__((ext_vector_type(8)));
using v8s = __attribute__((ext_vector_type(8))) short;   // bf16 x8 MFMA frag (4 VGPR)
using v4f = __attribute__((ext_vector_type(4))) float;   // f32 x4 acc frag

#define L_SEQ 2048
#define BATCH 8
#define NIN   1024    // 2H
#define WLD   3072    // W row stride, layers 1-3
#define NHALF 1536    // per-direction columns (3*H)
#define NROWS (L_SEQ*BATCH)
#define L2E   1.4426950408889634f

__device__ __forceinline__ float bits2f(unsigned short u){ return __uint_as_float(((unsigned)u)<<16); }
__device__ __forceinline__ float b2f(bf16 v){ return __bfloat162float(v); }
__device__ __forceinline__ bf16  f2b(float v){ return __float2bfloat16(v); }

__device__ __forceinline__ void gload16(const void* g, void* l){
    __builtin_amdgcn_global_load_lds((const __attribute__((address_space(1))) void*)g,
                                     (__attribute__((address_space(3))) void*)l, 16, 0, 0);
}

__global__ void k_code(float* __restrict__ out, float v){
    if (threadIdx.x == 0 && blockIdx.x == 0) out[0] = v;
}

// ---------------- dxT[b][l] = X[b][l] - X[b][l-1], 0 at l=0  ((B,L) layout)
__global__ __launch_bounds__(256) void k_diff(const float* __restrict__ X, float* __restrict__ dxT){
    int i = blockIdx.x*256 + threadIdx.x;
    if (i >= NROWS) return;
    int l = i & (L_SEQ-1);
    float v = 0.f;
    if (l > 0) v = X[i] - X[i-1];
    dxT[i] = v;
}

// ---------------- W (fp32 [1024][3072]) -> Wt (bf16 [3072][1024], transposed)
__global__ __launch_bounds__(256) void k_wt(const float* __restrict__ W, bf16* __restrict__ Wt){
    __shared__ float t[32][33];
    int k0 = blockIdx.x*32, n0 = blockIdx.y*32;
    int tx = threadIdx.x & 31, ty = threadIdx.x >> 5;   // ty 0..7
    #pragma unroll
    for (int j=0;j<4;j++)
        t[ty*4+j][tx] = W[(size_t)(k0+ty*4+j)*WLD + n0 + tx];
    __syncthreads();
    #pragma unroll
    for (int j=0;j<4;j++)
        Wt[(size_t)(n0+ty*4+j)*NIN + k0 + tx] = f2b(t[tx][ty*4+j]);
}

// ---------------- layer 0: PRODUCER/CONSUMER WAVE SPECIALIZATION (k_rec round-24 pattern).
// 128 blocks x 128 threads (2 waves). Block owns (d, b, 64-ch slice). Wave0 = f-gate chain
// (xv from LDS sdx, cs -> 2-buffer LDS). Wave1 = post of group g-1 (r/blend/global store).
// No global staging: dx column is LDS-resident. One lgkmcnt(0)+barrier per 16-step group.
__global__ __launch_bounds__(128) void k_layer0(const float* __restrict__ dxT, const float* __restrict__ W0,
                                                const float* __restrict__ wc, const float* __restrict__ bb,
                                                bf16* __restrict__ xout){
    __shared__ float sdx[L_SEQ];
    __shared__ float csb[2][1024];  // [buf][step*64+lane]
    int tid = threadIdx.x;
    int wv = tid >> 6, lane = tid & 63;
    int bid = blockIdx.x;           // 0..127
    int d = bid >> 6, b = (bid >> 3) & 7, hbase = (bid & 7)*64;
    int h = hbase + lane;
    int dcol = d*512 + h;
    const float* dxp = dxT + b*L_SEQ;
    for (int t = tid; t < L_SEQ; t += 128) sdx[t] = dxp[t];
    __syncthreads();

    float w0  = W0[d*2048 + h];
    float w1L = W0[d*2048 + 512 + h]*L2E;
    float w2L = W0[d*2048 + 1024 + h]*L2E;
    float w3  = W0[d*2048 + 1536 + h];
    float vfL = wc[dcol]*L2E,  vrL = wc[1024 + dcol]*L2E;
    float bfvL = bb[dcol]*L2E, brvL = bb[1024 + dcol]*L2E;
    float c = 0.f;
    ptrdiff_t xs = d ? -(ptrdiff_t)(BATCH*NIN) : (ptrdiff_t)(BATCH*NIN);

#define L0POST(gp_) do{                                                         \
        int s0_ = (gp_)*16;                                                     \
        bf16* xq_ = xout + ((size_t)(d ? (L_SEQ-1-s0_) : s0_)*BATCH + b)*NIN + dcol; \
        _Pragma("unroll")                                                       \
        for (int i_=0;i_<16;i_++){                                              \
            int s_ = s0_ + i_;                                                  \
            float xv_ = sdx[d ? (L_SEQ-1-s_) : s_];                             \
            float cs_ = csb[(gp_) & 1][i_*64 + lane];                           \
            float P2_ = fmaf(xv_, w2L, brvL);                                   \
            float P3_ = xv_*w3;                                                 \
            float e2_ = exp2f(fmaf(-vrL, cs_, -P2_));                           \
            float r_ = __builtin_amdgcn_rcpf(1.f + e2_);                        \
            xq_[(ptrdiff_t)i_*xs] = f2b(fmaf(r_, cs_ - P3_, P3_));              \
        }                                                                       \
    }while(0)

    for (int g = 0; g < 128; ++g){
        if (wv == 0){
            #pragma unroll
            for (int i = 0; i < 16; ++i){
                int s = g*16 + i;
                float xv = sdx[d ? (L_SEQ-1-s) : s];
                float P0 = xv*w0;
                float P1 = fmaf(xv, w1L, bfvL);
                float e = exp2f(fmaf(-vfL, c, -P1));
                float f = __builtin_amdgcn_rcpf(1.f + e);
                c = fmaf(f, c - P0, P0);
                csb[g & 1][i*64 + lane] = c;
            }
        } else if (g > 0){
            L0POST(g-1);
        }
        __builtin_amdgcn_sched_barrier(0);
        asm volatile("s_waitcnt lgkmcnt(0)" ::: "memory");   // cs writes visible / reads done
        __builtin_amdgcn_sched_barrier(0);
        __builtin_amdgcn_s_barrier();
    }
    if (wv == 1) L0POST(127);
#undef L0POST
}

// ---------------- MFMA GEMM: UcH[set s] = x[all rows] @ Wt[set s]^T   (bf16 output, unchanged)
__global__ __launch_bounds__(256) void k_gemm(const bf16* __restrict__ Xin, const bf16* __restrict__ Wt,
                                              bf16* __restrict__ Uc, int l0, int C){
    __shared__ bf16 As[3][4096];   // [buf][128 m][32 k], 64B rows (8KB/buf)
    __shared__ bf16 Bs[3][4096];
    int tid = threadIdx.x;
    int lane = tid & 63;
    int s = blockIdx.z;
    int base = (s == 0) ? l0 : (L_SEQ - l0 - C);
    const bf16* A  = Xin + (size_t)base*BATCH*NIN;
    const bf16* Bm = Wt + (size_t)s*NHALF*NIN;
    bf16*       Cc = Uc + (size_t)s*(size_t)C*BATCH*NHALF;

    int m0 = blockIdx.x*128, n0 = blockIdx.y*128;
    int wv = tid >> 6;
    int wm = (wv >> 1)*64, wn = (wv & 1)*64;

    v4f acc[4][4];
    #pragma unroll
    for (int i=0;i<4;i++)
        #pragma unroll
        for (int j=0;j<4;j++)
            #pragma unroll
            for (int r=0;r<4;r++) acc[i][j][r] = 0.f;

    int row_a = tid >> 2;
    int kb = (((tid & 3) ^ ((tid >> 3) & 3)))*8;            // source-side swizzle
    int wbase = (tid & 192)*16;
    int fro = (lane & 15)*64 + (((lane >> 4) ^ (((lane & 15) >> 1) & 3)))*16;  // read-side swizzle

#define STAGE(q, k0) do{                                                        \
        char* la_ = (char*)As[0] + (q)*8192;                                    \
        char* lb_ = (char*)Bs[0] + (q)*8192;                                    \
        gload16(A  + (size_t)(m0 + row_a      )*NIN + (k0) + kb, la_ + wbase);  \
        gload16(A  + (size_t)(m0 + row_a + 64 )*NIN + (k0) + kb, la_ + 4096 + wbase); \
        gload16(Bm + (size_t)(n0 + row_a      )*NIN + (k0) + kb, lb_ + wbase);  \
        gload16(Bm + (size_t)(n0 + row_a + 64 )*NIN + (k0) + kb, lb_ + 4096 + wbase); \
    }while(0)

    STAGE(0, 0);
    STAGE(1, 32);
    int cur = 0;
    for (int it = 0; it < 32; ++it){
        if (it < 30){
            int nb = cur + 2; if (nb >= 3) nb -= 3;
            STAGE(nb, (it+2)*32);
            asm volatile("s_waitcnt vmcnt(8)" ::: "memory");   // drain tile-it (2 iters old)
        } else if (it == 30){
            asm volatile("s_waitcnt vmcnt(4)" ::: "memory");
        } else {
            asm volatile("s_waitcnt vmcnt(0)" ::: "memory");
        }
        __builtin_amdgcn_sched_barrier(0);
        __builtin_amdgcn_s_barrier();
        const char* la = (const char*)As[0] + cur*8192;
        const char* lb = (const char*)Bs[0] + cur*8192;
        v8s av[4], bv[4];
        #pragma unroll
        for (int i=0;i<4;i++) av[i] = *(const v8s*)(la + (wm + i*16)*64 + fro);
        #pragma unroll
        for (int j=0;j<4;j++) bv[j] = *(const v8s*)(lb + (wn + j*16)*64 + fro);
        #pragma unroll
        for (int i=0;i<4;i++)
            #pragma unroll
            for (int j=0;j<4;j++)
                acc[i][j] = __builtin_amdgcn_mfma_f32_16x16x32_bf16(av[i], bv[j], acc[i][j], 0, 0, 0);
        __builtin_amdgcn_s_barrier();
        cur = cur + 1; if (cur == 3) cur = 0;
    }
#undef STAGE

    int cr = (lane >> 4)*4, ccol = lane & 15;
    #pragma unroll
    for (int i=0;i<4;i++){
        #pragma unroll
        for (int j=0;j<4;j++){
            size_t rb = (size_t)(m0 + wm + i*16 + cr)*NHALF + (n0 + wn + j*16 + ccol);
            #pragma unroll
            for (int r=0;r<4;r++) Cc[rb + (size_t)r*NHALF] = f2b(acc[i][j][r]);
        }
    }
}

// ---------------- recurrence, layers 1-3: producer/consumer wave specialization (round-24)
__global__ __launch_bounds__(128) void k_rec(const bf16* __restrict__ Uc, const bf16* __restrict__ xin,
                                             bf16* __restrict__ xout, float* __restrict__ carry,
                                             const float* __restrict__ wc, const float* __restrict__ bb,
                                             int l0, int C){
    __shared__ bf16  Ub[3][3072];   // [buf][seg=step*3+gate][64 bf16]  3x6KB
    __shared__ bf16  Xb[3][1024];   // [buf][step][64 bf16]             3x2KB
    __shared__ float csb[2][1024];  // [buf][step][64 f32]              2x4KB
    int tid = threadIdx.x;
    int wv = tid >> 6, lane = tid & 63;
    int bid = blockIdx.x;           // 0..127
    int d = bid >> 6, b = (bid >> 3) & 7, hbase = (bid & 7)*64;
    int h = hbase + lane;
    int dcol = d*512 + h;
    int ch = d*4096 + b*512 + h;
    float vfL = wc[d*512 + h]*L2E, vrL = wc[1024 + d*512 + h]*L2E;
    float bfvL = bb[d*512 + h]*L2E, brvL = bb[1024 + d*512 + h]*L2E;
    float c = (l0 == 0) ? 0.f : carry[ch];

    const bf16* Ubase = Uc + (size_t)d*(size_t)C*12288 + b*1536 + hbase;   // row stride 12288 bf16
    int lo3 = lane >> 3, ci8 = (lane & 7)*8;
    int ngrp = C >> 4;

#define RST_W0(base_, q_) do{                                                   \
        char* ub_ = (char*)Ub[q_];                                              \
        _Pragma("unroll")                                                       \
        for (int qq=0; qq<3; ++qq){                                             \
            int seg = qq*8 + lo3;                                               \
            int st_ = seg/3, gate_ = seg - st_*3;                               \
            int ss_ = (base_) + st_;                                            \
            int row_ = d ? (C-1-ss_) : ss_;                                     \
            gload16(Ubase + (size_t)row_*12288 + gate_*512 + ci8,               \
                    ub_ + qq*1024);                                             \
        }                                                                       \
    }while(0)

#define RST_W1(base_, q_) do{                                                   \
        char* ub_ = (char*)Ub[q_]; char* xb_ = (char*)Xb[q_];                   \
        _Pragma("unroll")                                                       \
        for (int qq=3; qq<6; ++qq){                                             \
            int seg = qq*8 + lo3;                                               \
            int st_ = seg/3, gate_ = seg - st_*3;                               \
            int ss_ = (base_) + st_;                                            \
            int row_ = d ? (C-1-ss_) : ss_;                                     \
            gload16(Ubase + (size_t)row_*12288 + gate_*512 + ci8,               \
                    ub_ + qq*1024);                                             \
        }                                                                       \
        _Pragma("unroll")                                                       \
        for (int j=0;j<2;++j){                                                  \
            int st_ = (base_) + j*8 + lo3;                                      \
            int t_  = d ? (L_SEQ-1 - l0 - st_) : (l0 + st_);                    \
            gload16(xin + ((size_t)t_*BATCH + b)*NIN + d*512 + hbase + ci8,     \
                    xb_ + j*1024);                                              \
        }                                                                       \
    }while(0)

#define DSR(dst, o) asm volatile("ds_read_u16 %0, %1 offset:" #o : "=v"(dst) : "v"(ab))

#define CHAIN(q_, qc_) do{                                                      \
        unsigned ab = (unsigned)(size_t)&Ub[q_][lane];                          \
        unsigned t0_[16], t1_[16];                                              \
        DSR(t0_[0] ,0);    DSR(t1_[0] ,128);                                    \
        DSR(t0_[1] ,384);  DSR(t1_[1] ,512);                                    \
        DSR(t0_[2] ,768);  DSR(t1_[2] ,896);                                    \
        DSR(t0_[3] ,1152); DSR(t1_[3] ,1280);                                   \
        DSR(t0_[4] ,1536); DSR(t1_[4] ,1664);                                   \
        DSR(t0_[5] ,1920); DSR(t1_[5] ,2048);                                   \
        DSR(t0_[6] ,2304); DSR(t1_[6] ,2432);                                   \
        DSR(t0_[7] ,2688); DSR(t1_[7] ,2816);                                   \
        DSR(t0_[8] ,3072); DSR(t1_[8] ,3200);                                   \
        DSR(t0_[9] ,3456); DSR(t1_[9] ,3584);                                   \
        DSR(t0_[10],3840); DSR(t1_[10],3968);                                   \
        DSR(t0_[11],4224); DSR(t1_[11],4352);                                   \
        DSR(t0_[12],4608); DSR(t1_[12],4736);                                   \
        DSR(t0_[13],4992); DSR(t1_[13],5120);                                   \
        DSR(t0_[14],5376); DSR(t1_[14],5504);                                   \
        DSR(t0_[15],5760); DSR(t1_[15],5888);                                   \
        asm volatile("s_waitcnt lgkmcnt(0)" ::: "memory");                      \
        __builtin_amdgcn_sched_barrier(0);                                      \
        _Pragma("unroll")                                                       \
        for (int i_=0;i_<16;i_++){                                              \
            float u0_ = __uint_as_float(t0_[i_]<<16);                           \
            float u1L_= fmaf(__uint_as_float(t1_[i_]<<16), L2E, bfvL);          \
            float e_ = exp2f(fmaf(-vfL, c, -u1L_));                             \
            float f_ = __builtin_amdgcn_rcpf(1.f + e_);                         \
            c = fmaf(f_, c - u0_, u0_);                                         \
            csb[qc_][i_*64 + lane] = c;                                         \
        }                                                                       \
    }while(0)

#define POST(gp_, qp_, qcp_) do{                                                \
        bf16* xq_ = xout + ((size_t)(d ? (L_SEQ-1 - l0 - (gp_)*16) : (l0 + (gp_)*16))*BATCH + b)*NIN + dcol; \
        ptrdiff_t xs_ = d ? -(ptrdiff_t)(BATCH*NIN) : (ptrdiff_t)(BATCH*NIN);   \
        _Pragma("unroll")                                                       \
        for (int i_=0;i_<16;i_++){                                              \
            float cs_ = csb[qcp_][i_*64 + lane];                                \
            float u2L_ = fmaf(b2f(Ub[qp_][(i_*3+2)*64 + lane]), L2E, brvL);     \
            float xr_  = b2f(Xb[qp_][i_*64 + lane]);                            \
            float e2_ = exp2f(fmaf(-vrL, cs_, -u2L_));                          \
            float r_ = __builtin_amdgcn_rcpf(1.f + e2_);                        \
            xq_[(ptrdiff_t)i_*xs_] = f2b(fmaf(r_, cs_-xr_, xr_));               \
        }                                                                       \
    }while(0)

    if (wv == 0) RST_W0(0, 0); else RST_W1(0, 0);
    asm volatile("s_waitcnt vmcnt(0)" ::: "memory");
    __builtin_amdgcn_sched_barrier(0);
    __builtin_amdgcn_s_barrier();

    int q0 = 0;
    for (int g = 0; g < ngrp; ++g){
        int qn = q0 + 1; if (qn == 3) qn = 0;
        if (g + 1 < ngrp){
            if (wv == 0){
                RST_W0((g+1)*16, qn);
                asm volatile("s_waitcnt vmcnt(3)" ::: "memory");     // drain L(g): newer = L(g+1)3
            } else {
                RST_W1((g+1)*16, qn);
                if (g < 2) asm volatile("s_waitcnt vmcnt(5)" ::: "memory");   // no stores yet
                else       asm volatile("s_waitcnt vmcnt(21)" ::: "memory");  // newer = S16 + L(g+1)5
            }
        } else {
            if (wv == 0) asm volatile("s_waitcnt vmcnt(0)" ::: "memory");
            else         asm volatile("s_waitcnt vmcnt(16)" ::: "memory");    // newer = S16
        }
        __builtin_amdgcn_sched_barrier(0);
        __builtin_amdgcn_s_barrier();        // Ub/Xb[g] resident (both staging halves)

        if (wv == 0){
            CHAIN(q0, g & 1);
        } else if (g > 0){
            int qp = q0 + 2; if (qp >= 3) qp -= 3;     // buffer of group g-1
            POST(g-1, qp, (g-1) & 1);
        }
        __builtin_amdgcn_sched_barrier(0);
        asm volatile("s_waitcnt lgkmcnt(0)" ::: "memory");   // cs writes visible; LDS reads done
        __builtin_amdgcn_sched_barrier(0);
        __builtin_amdgcn_s_barrier();        // orders cs(g) vs read(g+1); post(g-1) vs restage
        q0 = qn;
    }
    if (wv == 1){
        int qp = q0 + 2; if (qp >= 3) qp -= 3;         // buffer of group ngrp-1
        POST(ngrp-1, qp, (ngrp-1) & 1);
    } else {
        carry[ch] = c;
    }
#undef RST_W0
#undef RST_W1
#undef CHAIN
#undef POST
#undef DSR
}

// ---------------- classifier: out[(b*L + l)*3 + j] = h[row l*8+b] @ Wcls + bcls
__global__ __launch_bounds__(256) void k_cls(const bf16* __restrict__ Xf, const float* __restrict__ Wc,
                                             const float* __restrict__ bc, float* __restrict__ out){
    int wave = threadIdx.x >> 6, lane = threadIdx.x & 63;
    int row = blockIdx.x*4 + wave;                  // row = l*8+b
    const bf16* xp = Xf + (size_t)row*NIN + lane*16;
    u16x8 v0 = *(const u16x8*)(xp);
    u16x8 v1 = *(const u16x8*)(xp + 8);
    float a0=0.f, a1=0.f, a2=0.f;
    #pragma unroll
    for (int i=0;i<16;i++){
        float xv = bits2f(i<8 ? v0[i&7] : v1[i&7]);
        int k = lane*16 + i;
        a0 += xv*Wc[k*3+0];
        a1 += xv*Wc[k*3+1];
        a2 += xv*Wc[k*3+2];
    }
    #pragma unroll
    for (int off=32; off; off>>=1){
        a0 += __shfl_down(a0, off);
        a1 += __shfl_down(a1, off);
        a2 += __shfl_down(a2, off);
    }
    if (lane == 0){
        int l = row >> 3, b = row & 7;
        float* op = out + ((size_t)b*L_SEQ + l)*3;
        op[0] = a0 + bc[0];
        op[1] = a1 + bc[1];
        op[2] = a2 + bc[2];
    }
}

// ----------------------------------------------------------------
extern "C" void kernel_launch(void* const* d_in, const int* in_sizes, int n_in,
                              void* d_out, int out_size, void* d_ws, size_t ws_size,
                              hipStream_t stream){
    (void)in_sizes; (void)n_in; (void)out_size;
    const float* X    = (const float*)d_in[0];
    const float* W[4]  = {(const float*)d_in[1],(const float*)d_in[4],(const float*)d_in[7],(const float*)d_in[10]};
    const float* wc[4] = {(const float*)d_in[2],(const float*)d_in[5],(const float*)d_in[8],(const float*)d_in[11]};
    const float* bb[4] = {(const float*)d_in[3],(const float*)d_in[6],(const float*)d_in[9],(const float*)d_in[12]};
    const float* Wcls = (const float*)d_in[13];
    const float* bcls = (const float*)d_in[14];
    float* out = (float*)d_out;

    // workspace layout:
    //   xA    bf16[16384*1024]  @ 0           33,554,432
    //   xB    bf16[16384*1024]  @ 33554432    33,554,432
    //   dxT   f32 [8*2048]      @ 67108864        65,536
    //   carry f32 [8192]        @ 67174400        32,768
    //   Wt0-2 bf16[3072*1024]   @ 67207168    3 x 6,291,456
    //   Ucb   bf16[C*2*8*1536]  @ 86081536    C*49,152   (C=2048 -> 100MB)
    char*  ws    = (char*)d_ws;
    bf16*  xA    = (bf16*)ws;
    bf16*  xB    = (bf16*)(ws + 33554432);
    float* dxT   = (float*)(ws + 67108864);
    float* carry = (float*)(ws + 67174400);
    bf16*  Wt[3] = {(bf16*)(ws + 67207168), (bf16*)(ws + 73498624), (bf16*)(ws + 79790080)};
    bf16*  Ucb   = (bf16*)(ws + 86081536);
    const size_t NEEDED = 86081536ull + 64ull*49152ull;

    if (ws_size < NEEDED){
        float code = 1.0e6f + (float)((ws_size >> 20) > 9999 ? 9999 : (ws_size >> 20)) * 100.0f;
        k_code<<<1, 64, 0, stream>>>(out, code);
        return;
    }

    int C = 2048;
    while (C > 64 && 86081536ull + (size_t)C*49152ull > ws_size) C >>= 1;

    k_diff  <<<(NROWS+255)/256, 256, 0, stream>>>(X, dxT);
    for (int i = 0; i < 3; ++i)
        k_wt<<<dim3(32,96), 256, 0, stream>>>(W[i+1], Wt[i]);
    k_layer0<<<128, 128, 0, stream>>>(dxT, W[0], wc[0], bb[0], xA);

    bf16* xin = xA; bf16* xo = xB;
    for (int layer = 1; layer < 4; ++layer){
        for (int l0 = 0; l0 < L_SEQ; l0 += C){
            dim3 g(C*8/128, NHALF/128, 2);
            k_gemm<<<g, 256, 0, stream>>>(xin, Wt[layer-1], Ucb, l0, C);
            k_rec <<<128, 128, 0, stream>>>(Ucb, xin, xo, carry, wc[layer], bb[layer], l0, C);
        }
        bf16* t = xin; xin = xo; xo = t;
    }
    k_cls<<<NROWS/4, 256, 0, stream>>>(xin, Wcls, bcls, out);
}

// Round 26
// 910.793 us; speedup vs baseline: 1.9367x; 1.0542x over previous
//
#include <hip/hip_runtime.h>
#include <hip/hip_bf16.h>

typedef __hip_bfloat16 bf16;
typedef unsigned short u16x8 __attribute__((ext_vector_type(8)));
using v8s = __attribute__((ext_vector_type(8))) short;   // bf16 x8 MFMA frag (4 VGPR)
using v4f = __attribute__((ext_vector_type(4))) float;   // f32 x4 acc frag

#define L_SEQ 2048
#define BATCH 8
#define NIN   1024    // 2H
#define WLD   3072    // W row stride, layers 1-3
#define NHALF 1536    // per-direction columns (3*H)
#define NROWS (L_SEQ*BATCH)
#define L2E   1.4426950408889634f

__device__ __forceinline__ float bits2f(unsigned short u){ return __uint_as_float(((unsigned)u)<<16); }
__device__ __forceinline__ float b2f(bf16 v){ return __bfloat162float(v); }
__device__ __forceinline__ bf16  f2b(float v){ return __float2bfloat16(v); }

__device__ __forceinline__ void gload16(const void* g, void* l){
    __builtin_amdgcn_global_load_lds((const __attribute__((address_space(1))) void*)g,
                                     (__attribute__((address_space(3))) void*)l, 16, 0, 0);
}

__global__ void k_code(float* __restrict__ out, float v){
    if (threadIdx.x == 0 && blockIdx.x == 0) out[0] = v;
}

// ---------------- dxT[b][l] = X[b][l] - X[b][l-1], 0 at l=0  ((B,L) layout)
__global__ __launch_bounds__(256) void k_diff(const float* __restrict__ X, float* __restrict__ dxT){
    int i = blockIdx.x*256 + threadIdx.x;
    if (i >= NROWS) return;
    int l = i & (L_SEQ-1);
    float v = 0.f;
    if (l > 0) v = X[i] - X[i-1];
    dxT[i] = v;
}

// ---------------- W (fp32 [1024][3072]) -> Wt (bf16 [3072][1024], transposed)
__global__ __launch_bounds__(256) void k_wt(const float* __restrict__ W, bf16* __restrict__ Wt){
    __shared__ float t[32][33];
    int k0 = blockIdx.x*32, n0 = blockIdx.y*32;
    int tx = threadIdx.x & 31, ty = threadIdx.x >> 5;   // ty 0..7
    #pragma unroll
    for (int j=0;j<4;j++)
        t[ty*4+j][tx] = W[(size_t)(k0+ty*4+j)*WLD + n0 + tx];
    __syncthreads();
    #pragma unroll
    for (int j=0;j<4;j++)
        Wt[(size_t)(n0+ty*4+j)*NIN + k0 + tx] = f2b(t[tx][ty*4+j]);
}

// ---------------- layer 0: producer/consumer wave specialization (round-25, validated)
__global__ __launch_bounds__(128) void k_layer0(const float* __restrict__ dxT, const float* __restrict__ W0,
                                                const float* __restrict__ wc, const float* __restrict__ bb,
                                                bf16* __restrict__ xout){
    __shared__ float sdx[L_SEQ];
    __shared__ float csb[2][1024];  // [buf][step*64+lane]
    int tid = threadIdx.x;
    int wv = tid >> 6, lane = tid & 63;
    int bid = blockIdx.x;           // 0..127
    int d = bid >> 6, b = (bid >> 3) & 7, hbase = (bid & 7)*64;
    int h = hbase + lane;
    int dcol = d*512 + h;
    const float* dxp = dxT + b*L_SEQ;
    for (int t = tid; t < L_SEQ; t += 128) sdx[t] = dxp[t];
    __syncthreads();

    float w0  = W0[d*2048 + h];
    float w1L = W0[d*2048 + 512 + h]*L2E;
    float w2L = W0[d*2048 + 1024 + h]*L2E;
    float w3  = W0[d*2048 + 1536 + h];
    float vfL = wc[dcol]*L2E,  vrL = wc[1024 + dcol]*L2E;
    float bfvL = bb[dcol]*L2E, brvL = bb[1024 + dcol]*L2E;
    float c = 0.f;
    ptrdiff_t xs = d ? -(ptrdiff_t)(BATCH*NIN) : (ptrdiff_t)(BATCH*NIN);

#define L0POST(gp_) do{                                                         \
        int s0_ = (gp_)*16;                                                     \
        bf16* xq_ = xout + ((size_t)(d ? (L_SEQ-1-s0_) : s0_)*BATCH + b)*NIN + dcol; \
        _Pragma("unroll")                                                       \
        for (int i_=0;i_<16;i_++){                                              \
            int s_ = s0_ + i_;                                                  \
            float xv_ = sdx[d ? (L_SEQ-1-s_) : s_];                             \
            float cs_ = csb[(gp_) & 1][i_*64 + lane];                           \
            float P2_ = fmaf(xv_, w2L, brvL);                                   \
            float P3_ = xv_*w3;                                                 \
            float e2_ = exp2f(fmaf(-vrL, cs_, -P2_));                           \
            float r_ = __builtin_amdgcn_rcpf(1.f + e2_);                        \
            xq_[(ptrdiff_t)i_*xs] = f2b(fmaf(r_, cs_ - P3_, P3_));              \
        }                                                                       \
    }while(0)

    for (int g = 0; g < 128; ++g){
        if (wv == 0){
            #pragma unroll
            for (int i = 0; i < 16; ++i){
                int s = g*16 + i;
                float xv = sdx[d ? (L_SEQ-1-s) : s];
                float P0 = xv*w0;
                float P1 = fmaf(xv, w1L, bfvL);
                float e = exp2f(fmaf(-vfL, c, -P1));
                float f = __builtin_amdgcn_rcpf(1.f + e);
                c = fmaf(f, c - P0, P0);
                csb[g & 1][i*64 + lane] = c;
            }
        } else if (g > 0){
            L0POST(g-1);
        }
        __builtin_amdgcn_sched_barrier(0);
        asm volatile("s_waitcnt lgkmcnt(0)" ::: "memory");
        __builtin_amdgcn_sched_barrier(0);
        __builtin_amdgcn_s_barrier();
    }
    if (wv == 1) L0POST(127);
#undef L0POST
}

// ---------------- MFMA GEMM: UcH[set s] = x[all rows] @ Wt[set s]^T   (bf16 output, unchanged)
__global__ __launch_bounds__(256) void k_gemm(const bf16* __restrict__ Xin, const bf16* __restrict__ Wt,
                                              bf16* __restrict__ Uc, int l0, int C){
    __shared__ bf16 As[3][4096];   // [buf][128 m][32 k], 64B rows (8KB/buf)
    __shared__ bf16 Bs[3][4096];
    int tid = threadIdx.x;
    int lane = tid & 63;
    int s = blockIdx.z;
    int base = (s == 0) ? l0 : (L_SEQ - l0 - C);
    const bf16* A  = Xin + (size_t)base*BATCH*NIN;
    const bf16* Bm = Wt + (size_t)s*NHALF*NIN;
    bf16*       Cc = Uc + (size_t)s*(size_t)C*BATCH*NHALF;

    int m0 = blockIdx.x*128, n0 = blockIdx.y*128;
    int wv = tid >> 6;
    int wm = (wv >> 1)*64, wn = (wv & 1)*64;

    v4f acc[4][4];
    #pragma unroll
    for (int i=0;i<4;i++)
        #pragma unroll
        for (int j=0;j<4;j++)
            #pragma unroll
            for (int r=0;r<4;r++) acc[i][j][r] = 0.f;

    int row_a = tid >> 2;
    int kb = (((tid & 3) ^ ((tid >> 3) & 3)))*8;            // source-side swizzle
    int wbase = (tid & 192)*16;
    int fro = (lane & 15)*64 + (((lane >> 4) ^ (((lane & 15) >> 1) & 3)))*16;  // read-side swizzle

#define STAGE(q, k0) do{                                                        \
        char* la_ = (char*)As[0] + (q)*8192;                                    \
        char* lb_ = (char*)Bs[0] + (q)*8192;                                    \
        gload16(A  + (size_t)(m0 + row_a      )*NIN + (k0) + kb, la_ + wbase);  \
        gload16(A  + (size_t)(m0 + row_a + 64 )*NIN + (k0) + kb, la_ + 4096 + wbase); \
        gload16(Bm + (size_t)(n0 + row_a      )*NIN + (k0) + kb, lb_ + wbase);  \
        gload16(Bm + (size_t)(n0 + row_a + 64 )*NIN + (k0) + kb, lb_ + 4096 + wbase); \
    }while(0)

    STAGE(0, 0);
    STAGE(1, 32);
    int cur = 0;
    for (int it = 0; it < 32; ++it){
        if (it < 30){
            int nb = cur + 2; if (nb >= 3) nb -= 3;
            STAGE(nb, (it+2)*32);
            asm volatile("s_waitcnt vmcnt(8)" ::: "memory");   // drain tile-it (2 iters old)
        } else if (it == 30){
            asm volatile("s_waitcnt vmcnt(4)" ::: "memory");
        } else {
            asm volatile("s_waitcnt vmcnt(0)" ::: "memory");
        }
        __builtin_amdgcn_sched_barrier(0);
        __builtin_amdgcn_s_barrier();
        const char* la = (const char*)As[0] + cur*8192;
        const char* lb = (const char*)Bs[0] + cur*8192;
        v8s av[4], bv[4];
        #pragma unroll
        for (int i=0;i<4;i++) av[i] = *(const v8s*)(la + (wm + i*16)*64 + fro);
        #pragma unroll
        for (int j=0;j<4;j++) bv[j] = *(const v8s*)(lb + (wn + j*16)*64 + fro);
        #pragma unroll
        for (int i=0;i<4;i++)
            #pragma unroll
            for (int j=0;j<4;j++)
                acc[i][j] = __builtin_amdgcn_mfma_f32_16x16x32_bf16(av[i], bv[j], acc[i][j], 0, 0, 0);
        __builtin_amdgcn_s_barrier();
        cur = cur + 1; if (cur == 3) cur = 0;
    }
#undef STAGE

    int cr = (lane >> 4)*4, ccol = lane & 15;
    #pragma unroll
    for (int i=0;i<4;i++){
        #pragma unroll
        for (int j=0;j<4;j++){
            size_t rb = (size_t)(m0 + wm + i*16 + cr)*NHALF + (n0 + wn + j*16 + ccol);
            #pragma unroll
            for (int r=0;r<4;r++) Cc[rb + (size_t)r*NHALF] = f2b(acc[i][j][r]);
        }
    }
}

// ---------------- recurrence, layers 1-3: producer/consumer waves, 32-STEP groups.
// Round 26: double the group quantum to amortize the ~1900cy fixed overhead (2 barriers +
// 2 lgkm drains + skew) over 32 steps. Chain = two 16-step asm-ds_read sub-batches.
// LDS 64KB: Ub 3x12K, Xb 3x4K, csb 2x8K. Per-wave vmcnt: w0 steady(6)/tail(0);
// w1 g<2:(10), steady:(42)=S(g-2)32+L(g+1)10, tail:(32).
__global__ __launch_bounds__(128) void k_rec(const bf16* __restrict__ Uc, const bf16* __restrict__ xin,
                                             bf16* __restrict__ xout, float* __restrict__ carry,
                                             const float* __restrict__ wc, const float* __restrict__ bb,
                                             int l0, int C){
    __shared__ bf16  Ub[3][6144];   // [buf][seg=step*3+gate][64 bf16]  3x12KB (32 steps)
    __shared__ bf16  Xb[3][2048];   // [buf][step][64 bf16]             3x4KB
    __shared__ float csb[2][2048];  // [buf][step][64 f32]              2x8KB
    int tid = threadIdx.x;
    int wv = tid >> 6, lane = tid & 63;
    int bid = blockIdx.x;           // 0..127
    int d = bid >> 6, b = (bid >> 3) & 7, hbase = (bid & 7)*64;
    int h = hbase + lane;
    int dcol = d*512 + h;
    int ch = d*4096 + b*512 + h;
    float vfL = wc[d*512 + h]*L2E, vrL = wc[1024 + d*512 + h]*L2E;
    float bfvL = bb[d*512 + h]*L2E, brvL = bb[1024 + d*512 + h]*L2E;
    float c = (l0 == 0) ? 0.f : carry[ch];

    const bf16* Ubase = Uc + (size_t)d*(size_t)C*12288 + b*1536 + hbase;   // row stride 12288 bf16
    int lo3 = lane >> 3, ci8 = (lane & 7)*8;
    int ngrp = C >> 5;              // 32-step groups

#define RST_W0(base_, q_) do{                                                   \
        char* ub_ = (char*)Ub[q_];                                              \
        _Pragma("unroll")                                                       \
        for (int qq=0; qq<6; ++qq){                                             \
            int seg = qq*8 + lo3;                   /* 0..47 */                 \
            int st_ = seg/3, gate_ = seg - st_*3;                               \
            int ss_ = (base_) + st_;                                            \
            int row_ = d ? (C-1-ss_) : ss_;                                     \
            gload16(Ubase + (size_t)row_*12288 + gate_*512 + ci8,               \
                    ub_ + qq*1024);                                             \
        }                                                                       \
    }while(0)

#define RST_W1(base_, q_) do{                                                   \
        char* ub_ = (char*)Ub[q_]; char* xb_ = (char*)Xb[q_];                   \
        _Pragma("unroll")                                                       \
        for (int qq=6; qq<12; ++qq){                                            \
            int seg = qq*8 + lo3;                   /* 48..95 */                \
            int st_ = seg/3, gate_ = seg - st_*3;                               \
            int ss_ = (base_) + st_;                                            \
            int row_ = d ? (C-1-ss_) : ss_;                                     \
            gload16(Ubase + (size_t)row_*12288 + gate_*512 + ci8,               \
                    ub_ + qq*1024);                                             \
        }                                                                       \
        _Pragma("unroll")                                                       \
        for (int j=0;j<4;++j){                                                  \
            int st_ = (base_) + j*8 + lo3;                                      \
            int t_  = d ? (L_SEQ-1 - l0 - st_) : (l0 + st_);                    \
            gload16(xin + ((size_t)t_*BATCH + b)*NIN + d*512 + hbase + ci8,     \
                    xb_ + j*1024);                                              \
        }                                                                       \
    }while(0)

#define DSR(dst, o) asm volatile("ds_read_u16 %0, %1 offset:" #o : "=v"(dst) : "v"(ab))

// one 16-step chain sub-batch at LDS base addr ab, writing csb[qc_][(off_+i)*64+lane]
#define CHAIN16(qc_, off_) do{                                                  \
        unsigned t0_[16], t1_[16];                                              \
        DSR(t0_[0] ,0);    DSR(t1_[0] ,128);                                    \
        DSR(t0_[1] ,384);  DSR(t1_[1] ,512);                                    \
        DSR(t0_[2] ,768);  DSR(t1_[2] ,896);                                    \
        DSR(t0_[3] ,1152); DSR(t1_[3] ,1280);                                   \
        DSR(t0_[4] ,1536); DSR(t1_[4] ,1664);                                   \
        DSR(t0_[5] ,1920); DSR(t1_[5] ,2048);                                   \
        DSR(t0_[6] ,2304); DSR(t1_[6] ,2432);                                   \
        DSR(t0_[7] ,2688); DSR(t1_[7] ,2816);                                   \
        DSR(t0_[8] ,3072); DSR(t1_[8] ,3200);                                   \
        DSR(t0_[9] ,3456); DSR(t1_[9] ,3584);                                   \
        DSR(t0_[10],3840); DSR(t1_[10],3968);                                   \
        DSR(t0_[11],4224); DSR(t1_[11],4352);                                   \
        DSR(t0_[12],4608); DSR(t1_[12],4736);                                   \
        DSR(t0_[13],4992); DSR(t1_[13],5120);                                   \
        DSR(t0_[14],5376); DSR(t1_[14],5504);                                   \
        DSR(t0_[15],5760); DSR(t1_[15],5888);                                   \
        asm volatile("s_waitcnt lgkmcnt(0)" ::: "memory");                      \
        __builtin_amdgcn_sched_barrier(0);                                      \
        _Pragma("unroll")                                                       \
        for (int i_=0;i_<16;i_++){                                              \
            float u0_ = __uint_as_float(t0_[i_]<<16);                           \
            float u1L_= fmaf(__uint_as_float(t1_[i_]<<16), L2E, bfvL);          \
            float e_ = exp2f(fmaf(-vfL, c, -u1L_));                             \
            float f_ = __builtin_amdgcn_rcpf(1.f + e_);                         \
            c = fmaf(f_, c - u0_, u0_);                                         \
            csb[qc_][((off_)+i_)*64 + lane] = c;                                \
        }                                                                       \
    }while(0)

#define POST(gp_, qp_, qcp_) do{                                                \
        bf16* xq_ = xout + ((size_t)(d ? (L_SEQ-1 - l0 - (gp_)*32) : (l0 + (gp_)*32))*BATCH + b)*NIN + dcol; \
        ptrdiff_t xs_ = d ? -(ptrdiff_t)(BATCH*NIN) : (ptrdiff_t)(BATCH*NIN);   \
        _Pragma("unroll")                                                       \
        for (int i_=0;i_<32;i_++){                                              \
            float cs_ = csb[qcp_][i_*64 + lane];                                \
            float u2L_ = fmaf(b2f(Ub[qp_][(i_*3+2)*64 + lane]), L2E, brvL);     \
            float xr_  = b2f(Xb[qp_][i_*64 + lane]);                            \
            float e2_ = exp2f(fmaf(-vrL, cs_, -u2L_));                          \
            float r_ = __builtin_amdgcn_rcpf(1.f + e2_);                        \
            xq_[(ptrdiff_t)i_*xs_] = f2b(fmaf(r_, cs_-xr_, xr_));               \
        }                                                                       \
    }while(0)

    if (wv == 0) RST_W0(0, 0); else RST_W1(0, 0);
    asm volatile("s_waitcnt vmcnt(0)" ::: "memory");
    __builtin_amdgcn_sched_barrier(0);
    __builtin_amdgcn_s_barrier();

    int q0 = 0;
    for (int g = 0; g < ngrp; ++g){
        int qn = q0 + 1; if (qn == 3) qn = 0;
        if (g + 1 < ngrp){
            if (wv == 0){
                RST_W0((g+1)*32, qn);
                asm volatile("s_waitcnt vmcnt(6)" ::: "memory");     // newer = L(g+1)6
            } else {
                RST_W1((g+1)*32, qn);
                if (g < 2) asm volatile("s_waitcnt vmcnt(10)" ::: "memory");  // no stores yet
                else       asm volatile("s_waitcnt vmcnt(42)" ::: "memory");  // newer = S32 + L(g+1)10
            }
        } else {
            if (wv == 0) asm volatile("s_waitcnt vmcnt(0)" ::: "memory");
            else         asm volatile("s_waitcnt vmcnt(32)" ::: "memory");    // newer = S(g-2)32
        }
        __builtin_amdgcn_sched_barrier(0);
        __builtin_amdgcn_s_barrier();        // Ub/Xb[g] resident (both staging halves)

        if (wv == 0){
            unsigned ab = (unsigned)(size_t)&Ub[q0][lane];
            CHAIN16(g & 1, 0);
            ab += 6144;
            CHAIN16(g & 1, 16);
        } else if (g > 0){
            int qp = q0 + 2; if (qp >= 3) qp -= 3;     // buffer of group g-1
            POST(g-1, qp, (g-1) & 1);
        }
        __builtin_amdgcn_sched_barrier(0);
        asm volatile("s_waitcnt lgkmcnt(0)" ::: "memory");   // cs writes visible; LDS reads done
        __builtin_amdgcn_sched_barrier(0);
        __builtin_amdgcn_s_barrier();        // orders cs(g) vs read(g+1); post(g-1) vs restage
        q0 = qn;
    }
    if (wv == 1){
        int qp = q0 + 2; if (qp >= 3) qp -= 3;         // buffer of group ngrp-1
        POST(ngrp-1, qp, (ngrp-1) & 1);
    } else {
        carry[ch] = c;
    }
#undef RST_W0
#undef RST_W1
#undef CHAIN16
#undef POST
#undef DSR
}

// ---------------- classifier: out[(b*L + l)*3 + j] = h[row l*8+b] @ Wcls + bcls
__global__ __launch_bounds__(256) void k_cls(const bf16* __restrict__ Xf, const float* __restrict__ Wc,
                                             const float* __restrict__ bc, float* __restrict__ out){
    int wave = threadIdx.x >> 6, lane = threadIdx.x & 63;
    int row = blockIdx.x*4 + wave;                  // row = l*8+b
    const bf16* xp = Xf + (size_t)row*NIN + lane*16;
    u16x8 v0 = *(const u16x8*)(xp);
    u16x8 v1 = *(const u16x8*)(xp + 8);
    float a0=0.f, a1=0.f, a2=0.f;
    #pragma unroll
    for (int i=0;i<16;i++){
        float xv = bits2f(i<8 ? v0[i&7] : v1[i&7]);
        int k = lane*16 + i;
        a0 += xv*Wc[k*3+0];
        a1 += xv*Wc[k*3+1];
        a2 += xv*Wc[k*3+2];
    }
    #pragma unroll
    for (int off=32; off; off>>=1){
        a0 += __shfl_down(a0, off);
        a1 += __shfl_down(a1, off);
        a2 += __shfl_down(a2, off);
    }
    if (lane == 0){
        int l = row >> 3, b = row & 7;
        float* op = out + ((size_t)b*L_SEQ + l)*3;
        op[0] = a0 + bc[0];
        op[1] = a1 + bc[1];
        op[2] = a2 + bc[2];
    }
}

// ----------------------------------------------------------------
extern "C" void kernel_launch(void* const* d_in, const int* in_sizes, int n_in,
                              void* d_out, int out_size, void* d_ws, size_t ws_size,
                              hipStream_t stream){
    (void)in_sizes; (void)n_in; (void)out_size;
    const float* X    = (const float*)d_in[0];
    const float* W[4]  = {(const float*)d_in[1],(const float*)d_in[4],(const float*)d_in[7],(const float*)d_in[10]};
    const float* wc[4] = {(const float*)d_in[2],(const float*)d_in[5],(const float*)d_in[8],(const float*)d_in[11]};
    const float* bb[4] = {(const float*)d_in[3],(const float*)d_in[6],(const float*)d_in[9],(const float*)d_in[12]};
    const float* Wcls = (const float*)d_in[13];
    const float* bcls = (const float*)d_in[14];
    float* out = (float*)d_out;

    // workspace layout:
    //   xA    bf16[16384*1024]  @ 0           33,554,432
    //   xB    bf16[16384*1024]  @ 33554432    33,554,432
    //   dxT   f32 [8*2048]      @ 67108864        65,536
    //   carry f32 [8192]        @ 67174400        32,768
    //   Wt0-2 bf16[3072*1024]   @ 67207168    3 x 6,291,456
    //   Ucb   bf16[C*2*8*1536]  @ 86081536    C*49,152   (C=2048 -> 100MB)
    char*  ws    = (char*)d_ws;
    bf16*  xA    = (bf16*)ws;
    bf16*  xB    = (bf16*)(ws + 33554432);
    float* dxT   = (float*)(ws + 67108864);
    float* carry = (float*)(ws + 67174400);
    bf16*  Wt[3] = {(bf16*)(ws + 67207168), (bf16*)(ws + 73498624), (bf16*)(ws + 79790080)};
    bf16*  Ucb   = (bf16*)(ws + 86081536);
    const size_t NEEDED = 86081536ull + 64ull*49152ull;

    if (ws_size < NEEDED){
        float code = 1.0e6f + (float)((ws_size >> 20) > 9999 ? 9999 : (ws_size >> 20)) * 100.0f;
        k_code<<<1, 64, 0, stream>>>(out, code);
        return;
    }

    int C = 2048;
    while (C > 64 && 86081536ull + (size_t)C*49152ull > ws_size) C >>= 1;

    k_diff  <<<(NROWS+255)/256, 256, 0, stream>>>(X, dxT);
    for (int i = 0; i < 3; ++i)
        k_wt<<<dim3(32,96), 256, 0, stream>>>(W[i+1], Wt[i]);
    k_layer0<<<128, 128, 0, stream>>>(dxT, W[0], wc[0], bb[0], xA);

    bf16* xin = xA; bf16* xo = xB;
    for (int layer = 1; layer < 4; ++layer){
        for (int l0 = 0; l0 < L_SEQ; l0 += C){
            dim3 g(C*8/128, NHALF/128, 2);
            k_gemm<<<g, 256, 0, stream>>>(xin, Wt[layer-1], Ucb, l0, C);
            k_rec <<<128, 128, 0, stream>>>(Ucb, xin, xo, carry, wc[layer], bb[layer], l0, C);
        }
        bf16* t = xin; xin = xo; xo = t;
    }
    k_cls<<<NROWS/4, 256, 0, stream>>>(xin, Wcls, bcls, out);
}